// Round 9
// baseline (210.276 us; speedup 1.0000x reference)
//
#include <hip/hip_runtime.h>

constexpr int B_ = 4;
constexpr int N_ = 2048;
constexpr int NFEAT_ = 256;
constexpr int NHEADS_ = 8;
constexpr float SLOPE_ = 0.1f;
constexpr float L2E = 1.4426950408889634f;   // log2(e)

typedef __attribute__((ext_vector_type(8))) __fp16 f16x8;
typedef __attribute__((ext_vector_type(4))) __fp16 f16x4;
typedef __attribute__((ext_vector_type(2))) __fp16 f16x2;
typedef __attribute__((ext_vector_type(4))) float f32x4;

__device__ __forceinline__ f16x8 pack8(const float* v) {
  union { f16x2 h2[4]; f16x8 h8; } u;
  u.h2[0] = __builtin_amdgcn_cvt_pkrtz(v[0], v[1]);
  u.h2[1] = __builtin_amdgcn_cvt_pkrtz(v[2], v[3]);
  u.h2[2] = __builtin_amdgcn_cvt_pkrtz(v[4], v[5]);
  u.h2[3] = __builtin_amdgcn_cvt_pkrtz(v[6], v[7]);
  return u.h8;
}
__device__ __forceinline__ f16x4 pack4(float a, float b, float c, float d) {
  union { f16x2 h2[2]; f16x4 h4; } u;
  u.h2[0] = __builtin_amdgcn_cvt_pkrtz(a, b);
  u.h2[1] = __builtin_amdgcn_cvt_pkrtz(c, d);
  return u.h4;
}

// weight pair = max(Ep*E1pair, Eq*E2pair) in packed f16 (exp2 is monotone, so
// exp2(max(t0,t1)) == max(exp2 t0, exp2 t1); both branches factor row x col).
__device__ __forceinline__ unsigned int wmax(f16x2 Ep2, f16x2 Eq2,
                                             unsigned int e1p, unsigned int e2p) {
  f16x2 ea, eb;
  __builtin_memcpy(&ea, &e1p, 4);
  __builtin_memcpy(&eb, &e2p, 4);
  f16x2 a, b, c;
  asm("v_pk_mul_f16 %0, %1, %2" : "=v"(a) : "v"(Ep2), "v"(ea));
  asm("v_pk_mul_f16 %0, %1, %2" : "=v"(b) : "v"(Eq2), "v"(eb));
  asm("v_pk_max_f16 %0, %1, %2" : "=v"(c) : "v"(a), "v"(b));
  unsigned int r;
  __builtin_memcpy(&r, &c, 4);
  return r;
}

// ---------------------------------------------------------------------------
// Fused prep: blocks [0,4096) packmask; [4096,4160) prepWh; [4160,4192) prepWo
// ---------------------------------------------------------------------------
__global__ __launch_bounds__(256) void k_prep(
    const int* __restrict__ adj, unsigned short* __restrict__ mask2,
    const float* __restrict__ Wh, __fp16* __restrict__ WhB,
    const float* __restrict__ Wo, __fp16* __restrict__ WoB)
{
  const int bid = blockIdx.x;
  const int l = threadIdx.x & 63;
  if (bid < 4096) {
    const size_t gw = ((size_t)bid * 256 + threadIdx.x) >> 6;
    const int jt = (int)(gw & 31);
    const int ig16 = (int)((gw >> 5) & 127);
    const int b = (int)(gw >> 12);
    const int q = l >> 4, c15 = l & 15;
    const int* base = adj + ((size_t)b * N_ + ig16 * 16) * N_ + jt * 64 + l;
    unsigned int msk = 0;
    #pragma unroll
    for (int r = 0; r < 16; ++r) {
      int a = base[(size_t)r * N_];
      unsigned long long bal = __ballot(a > 0);
      unsigned int v = (unsigned int)((bal >> (q * 8)) & 0xffull)
                     | ((unsigned int)((bal >> (q * 8 + 32)) & 0xffull) << 8);
      if (r == c15) msk = v;
    }
    mask2[gw * 64 + l] = (unsigned short)msk;
  } else if (bid < 4160) {
    int s = (int)(((bid - 4096) * 256 + threadIdx.x) >> 6);   // 0..255
    int h = s >> 5, ks = (s >> 2) & 7, ft = s & 3;
    const float* src = Wh + ((size_t)h * 256 + ks * 32 + (l >> 4) * 8) * 64 + ft * 16 + (l & 15);
    float v[8];
    #pragma unroll
    for (int j = 0; j < 8; ++j) v[j] = src[(size_t)j * 64];
    *(f16x8*)(WhB + (size_t)s * 512 + l * 8) = pack8(v);
  } else {
    int s = (int)(((bid - 4160) * 256 + threadIdx.x) >> 6);   // 0..127
    int ks = s >> 3, ft = s & 7;
    const float* src = Wo + ((size_t)ks * 32 + (l >> 4) * 8) * 128 + ft * 16 + (l & 15);
    float v[8];
    #pragma unroll
    for (int j = 0; j < 8; ++j) v[j] = src[(size_t)j * 128];
    *(f16x8*)(WoB + (size_t)s * 512 + l * 8) = pack8(v);
  }
}

// ---------------------------------------------------------------------------
// GEMM1 (MFMA): block = 16 n-rows x ALL 512 f (8 heads), 256 thr = 4 waves.
// Epilogue emits exp2 column tables e1h/e2h + per-(block,head) partial max
// (plain store, NO atomics).
// ---------------------------------------------------------------------------
__global__ __launch_bounds__(256, 4) void k_gemm1(
    const float* __restrict__ x, const __fp16* __restrict__ WhB,
    const float* __restrict__ ah,
    __fp16* __restrict__ hB1, float* __restrict__ s1h,
    __fp16* __restrict__ e1h, __fp16* __restrict__ e2h,
    float* __restrict__ pmx1)
{
  constexpr int XP = 264;
  __shared__ __fp16 xs[16 * XP];
  __shared__ __fp16 hT[512 * 16];

  const int t = threadIdx.x;
  const int bid = blockIdx.x;
  const int b = bid >> 7;
  const int n0 = (bid & 127) * 16;

  {  // stage x -> f16
    int r = t >> 4, k0 = (t & 15) * 16;
    const float* src = x + ((size_t)(b * N_) + n0 + r) * NFEAT_ + k0;
    float v0[8], v1[8];
    *(float4*)&v0[0] = *(const float4*)(src);
    *(float4*)&v0[4] = *(const float4*)(src + 4);
    *(float4*)&v1[0] = *(const float4*)(src + 8);
    *(float4*)&v1[4] = *(const float4*)(src + 12);
    *(f16x8*)&xs[r * XP + k0] = pack8(v0);
    *(f16x8*)&xs[r * XP + k0 + 8] = pack8(v1);
  }
  __syncthreads();

  const int w = t >> 6, l = t & 63;
  const int quad = l >> 4, c15 = l & 15;

  f32x4 acc[8];
  #pragma unroll
  for (int i = 0; i < 8; ++i) acc[i] = (f32x4){0.f, 0.f, 0.f, 0.f};

  for (int ks = 0; ks < 8; ++ks) {
    f16x8 af = *(const f16x8*)&xs[c15 * XP + ks * 32 + quad * 8];
    #pragma unroll
    for (int tt = 0; tt < 8; ++tt) {
      int hl = tt >> 2, ft = tt & 3;
      f16x8 bf = *(const f16x8*)(WhB +
          ((((size_t)(2 * w + hl) * 8 + ks) * 4 + ft) * 512) + l * 8);
      acc[tt] = __builtin_amdgcn_mfma_f32_16x16x32_f16(af, bf, acc[tt], 0, 0, 0);
    }
  }

  #pragma unroll
  for (int hl = 0; hl < 2; ++hl) {
    int head = 2 * w + hl;
    float a1v[4], a2v[4];
    #pragma unroll
    for (int ft = 0; ft < 4; ++ft) {
      a1v[ft] = ah[head * 128 + ft * 16 + c15] * L2E;
      a2v[ft] = ah[head * 128 + 64 + ft * 16 + c15] * L2E;
    }
    float hmax = -1e30f;
    #pragma unroll
    for (int r = 0; r < 4; ++r) {
      float v1 = 0.f, v2 = 0.f;
      #pragma unroll
      for (int ft = 0; ft < 4; ++ft) {
        v1 = fmaf(acc[hl * 4 + ft][r], a1v[ft], v1);
        v2 = fmaf(acc[hl * 4 + ft][r], a2v[ft], v2);
      }
      #pragma unroll
      for (int off = 1; off < 16; off <<= 1) {
        v1 += __shfl_xor(v1, off, 64);
        v2 += __shfl_xor(v2, off, 64);
      }
      if (c15 == 0) {
        const size_t nn = (size_t)(b * NHEADS_ + head) * N_ + n0 + quad * 4 + r;
        s1h[nn] = v1;
        e1h[nn] = (__fp16)__builtin_amdgcn_exp2f(v2);
        e2h[nn] = (__fp16)__builtin_amdgcn_exp2f(SLOPE_ * v2);
      }
      hmax = fmaxf(hmax, v2);
    }
    hmax = fmaxf(hmax, __shfl_xor(hmax, 16, 64));
    hmax = fmaxf(hmax, __shfl_xor(hmax, 32, 64));
    if (l == 0)
      pmx1[(size_t)(b * NHEADS_ + head) * 128 + (n0 >> 4)] = hmax;
  }

  #pragma unroll
  for (int tt = 0; tt < 8; ++tt) {
    int f = (2 * w + (tt >> 2)) * 64 + (tt & 3) * 16 + c15;
    *(f16x4*)&hT[f * 16 + quad * 4] =
        pack4(acc[tt][0], acc[tt][1], acc[tt][2], acc[tt][3]);
  }
  __syncthreads();

  const int base_oct = (n0 >> 3) & 3;
  #pragma unroll
  for (int q = 0; q < 4; ++q) {
    int s = t + q * 256;
    int c15v = s & 15, oct = (s >> 4) & 1, ft = (s >> 5) & 3, head = s >> 7;
    f16x8 v = *(const f16x8*)&hT[(head * 64 + ft * 16 + c15v) * 16 + oct * 8];
    int lane0 = (base_oct + oct) * 16 + c15v;
    *(f16x8*)(hB1 +
        ((((size_t)(b * NHEADS_ + head) * 64 + (n0 >> 5)) * 4 + ft) * 512) + lane0 * 8) = v;
  }
}

// ---------------------------------------------------------------------------
// GEMM2 (MFMA): block = 16 n-rows x 128 f, 256 thr = 4 waves.
// Epilogue emits e1o/e2o tables + per-block partial max (plain store).
// ---------------------------------------------------------------------------
__global__ __launch_bounds__(256, 4) void k_gemm2(
    const __fp16* __restrict__ g1, const __fp16* __restrict__ WoB,
    const float* __restrict__ ao,
    __fp16* __restrict__ hB2, float* __restrict__ s1o,
    __fp16* __restrict__ e1o, __fp16* __restrict__ e2o,
    float* __restrict__ pmx2)
{
  constexpr int GP = 520;
  __shared__ __fp16 gs[16 * GP];
  __shared__ __fp16 hT[128 * 16];
  __shared__ float sd1[4][16], sd2[4][16];

  const int t = threadIdx.x;
  const int bid = blockIdx.x;
  const int b = bid >> 7;
  const int n0 = (bid & 127) * 16;

  {
    int r = t >> 4, k0 = (t & 15) * 32;
    const __fp16* src = g1 + ((size_t)(b * N_) + n0 + r) * 512 + k0;
    #pragma unroll
    for (int i = 0; i < 4; ++i)
      *(f16x8*)&gs[r * GP + k0 + i * 8] = *(const f16x8*)(src + i * 8);
  }
  __syncthreads();

  const int w = t >> 6, l = t & 63;
  const int quad = l >> 4, c15 = l & 15;

  f32x4 acc[2];
  acc[0] = (f32x4){0.f, 0.f, 0.f, 0.f};
  acc[1] = (f32x4){0.f, 0.f, 0.f, 0.f};

  for (int ks = 0; ks < 16; ++ks) {
    f16x8 af = *(const f16x8*)&gs[c15 * GP + ks * 32 + quad * 8];
    #pragma unroll
    for (int tt = 0; tt < 2; ++tt) {
      int ft = 2 * w + tt;
      f16x8 bf = *(const f16x8*)(WoB + (((size_t)ks * 8 + ft) * 512) + l * 8);
      acc[tt] = __builtin_amdgcn_mfma_f32_16x16x32_f16(af, bf, acc[tt], 0, 0, 0);
    }
  }

  {
    float a1v[2], a2v[2];
    #pragma unroll
    for (int tt = 0; tt < 2; ++tt) {
      int f = (2 * w + tt) * 16 + c15;
      a1v[tt] = ao[f] * L2E;
      a2v[tt] = ao[128 + f] * L2E;
    }
    #pragma unroll
    for (int r = 0; r < 4; ++r) {
      float v1 = acc[0][r] * a1v[0] + acc[1][r] * a1v[1];
      float v2 = acc[0][r] * a2v[0] + acc[1][r] * a2v[1];
      #pragma unroll
      for (int off = 1; off < 16; off <<= 1) {
        v1 += __shfl_xor(v1, off, 64);
        v2 += __shfl_xor(v2, off, 64);
      }
      if (c15 == 0) { sd1[w][quad * 4 + r] = v1; sd2[w][quad * 4 + r] = v2; }
    }
  }

  #pragma unroll
  for (int tt = 0; tt < 2; ++tt) {
    int f = (2 * w + tt) * 16 + c15;
    *(f16x4*)&hT[f * 16 + quad * 4] =
        pack4(acc[tt][0], acc[tt][1], acc[tt][2], acc[tt][3]);
  }
  __syncthreads();

  if (t < 16)
    s1o[(size_t)b * N_ + n0 + t] = sd1[0][t] + sd1[1][t] + sd1[2][t] + sd1[3][t];
  else if (t < 32) {
    int rr = t - 16;
    float v = sd2[0][rr] + sd2[1][rr] + sd2[2][rr] + sd2[3][rr];
    e1o[(size_t)b * N_ + n0 + rr] = (__fp16)__builtin_amdgcn_exp2f(v);
    e2o[(size_t)b * N_ + n0 + rr] = (__fp16)__builtin_amdgcn_exp2f(SLOPE_ * v);
    float hm = v;
    hm = fmaxf(hm, __shfl_xor(hm, 1, 64));
    hm = fmaxf(hm, __shfl_xor(hm, 2, 64));
    hm = fmaxf(hm, __shfl_xor(hm, 4, 64));
    hm = fmaxf(hm, __shfl_xor(hm, 8, 64));
    if (rr == 0) pmx2[(size_t)b * 128 + (n0 >> 4)] = hm;
  }

  {
    int c15v = t & 15, oct = (t >> 4) & 1, ft = t >> 5;
    f16x8 v = *(const f16x8*)&hT[(ft * 16 + c15v) * 16 + oct * 8];
    int base_oct = (n0 >> 3) & 3;
    int lane0 = (base_oct + oct) * 16 + c15v;
    *(f16x8*)(hB2 +
        (((size_t)(b * 64 + (n0 >> 5)) * 8 + ft) * 512) + lane0 * 8) = v;
  }
}

// ---------------------------------------------------------------------------
// ATT1 (LDS-amortized): block = 128 rows, 4 waves x 32 rows; each wave holds
// TWO 16-row A-fragments (afA rows i0w.., afB rows i0w+16..) so every vbuf
// and ets LDS read is consumed twice (10 MFMA per read set instead of 5).
// Per-CU b128 LDS ops halve (~6.7K -> ~3.6K); att1 was LDS-pipe-bound
// (6.7K x 12cy = 33us = measured). TJ=128 shared dbuf tile, depth-2 reg
// staging, factorized weights, pmx row max. Grid 512 x 256 thr.
// ---------------------------------------------------------------------------
__global__ __launch_bounds__(256, 4) void k_att1(
    const __fp16* __restrict__ hB, const float* __restrict__ s1,
    const __fp16* __restrict__ e1, const __fp16* __restrict__ e2,
    const float* __restrict__ pmx1,
    const unsigned short* __restrict__ mask2,
    const float* __restrict__ bias, __fp16* __restrict__ g1)
{
  constexpr int TJ = 128, NIT = N_ / TJ;       // 16 iterations
  constexpr int TILE = TJ * 64;                // 8192 f16 = 16 KB / slot

  __shared__ __fp16 vbuf[2][TILE];             // 32 KB (shared by all 4 waves)
  __shared__ __fp16 ets[2][N_];                // 8 KB (E1, E2 tables)
  __shared__ uint2 mlut[16];                   // nibble -> 2 packed pair masks

  const int tid = threadIdx.x;                 // 0..255
  const int w = tid >> 6, l = tid & 63;
  const int quad = l >> 4, c15 = l & 15;

  int idx = blockIdx.x;
  const int ig = idx & 15; idx >>= 4;          // N/128 = 16 row-tiles
  const int head = idx & 7;
  const int b = idx >> 3;
  const int i0w = ig * 128 + w * 32;           // wave's 32 rows (2x16)
  const int bh = b * NHEADS_ + head;

  const float* s1p = s1 + (size_t)bh * N_;
  const char* hBp = (const char*)(hB + (size_t)bh * (N_ / 32) * 2048);
  const unsigned short* mpA = mask2 + ((size_t)(b * 128 + (i0w >> 4)) * 32) * 64 + l;
  const unsigned short* mpB = mpA + 32 * 64;   // next 16-row group

  if (tid < 16) {
    unsigned int v = tid;
    mlut[tid] = (uint2){ ((v & 1u) ? 0xffffu : 0u) | ((v & 2u) ? 0xffff0000u : 0u),
                         ((v & 4u) ? 0xffffu : 0u) | ((v & 8u) ? 0xffff0000u : 0u) };
  }

  // depth-2 prologue: tiles 0 and 1 in flight (16 KB each, 4 float4/thread)
  float4 pA[4], pB[4];
  #pragma unroll
  for (int i = 0; i < 4; ++i) {
    pA[i] = *(const float4*)(hBp + i * 4096 + tid * 16);
    pB[i] = *(const float4*)(hBp + 16384 + i * 4096 + tid * 16);
  }
  unsigned short mkA0 = mpA[0], mkA1 = mpA[64];
  unsigned short mkB0 = mpB[0], mkB1 = mpB[64];

  {  // stage E tables: 256 threads x 32 B covers both 4 KB tables
    const int half = tid >> 7, off = (tid & 127) * 16;
    const __fp16* src = (half ? e2 : e1) + (size_t)bh * N_ + off;
    *(f16x8*)&ets[half][off] = *(const f16x8*)src;
    *(f16x8*)&ets[half][off + 8] = *(const f16x8*)(src + 8);
  }

  const float s1vA = s1p[i0w + c15];
  const float s1vB = s1p[i0w + 16 + c15];
  // row max of s2 from the 128 partials (every wave redundantly)
  float s2m;
  {
    const float* pm = pmx1 + (size_t)bh * 128;
    float tmx = fmaxf(pm[l], pm[l + 64]);
    #pragma unroll
    for (int off = 1; off < 64; off <<= 1)
      tmx = fmaxf(tmx, __shfl_xor(tmx, off, 64));
    s2m = tmx;
  }
  // write tile 0 (vmcnt on pA elapsed under the staging above)
  #pragma unroll
  for (int i = 0; i < 4; ++i)
    *(float4*)((char*)&vbuf[0][0] + i * 4096 + tid * 16) = pA[i];
  __syncthreads();

  const float zmA = s1vA + s2m;
  const float mA_ = fmaxf(zmA, SLOPE_ * zmA);
  const float EpA = __builtin_amdgcn_exp2f(s1vA - mA_);
  const float EqA = __builtin_amdgcn_exp2f(SLOPE_ * s1vA - mA_);
  const f16x2 EpA2 = __builtin_amdgcn_cvt_pkrtz(EpA, EpA);
  const f16x2 EqA2 = __builtin_amdgcn_cvt_pkrtz(EqA, EqA);
  const float zmB = s1vB + s2m;
  const float mB_ = fmaxf(zmB, SLOPE_ * zmB);
  const float EpB = __builtin_amdgcn_exp2f(s1vB - mB_);
  const float EqB = __builtin_amdgcn_exp2f(SLOPE_ * s1vB - mB_);
  const f16x2 EpB2 = __builtin_amdgcn_cvt_pkrtz(EpB, EpB);
  const f16x2 EqB2 = __builtin_amdgcn_cvt_pkrtz(EqB, EqB);

  f16x8 ones;
  #pragma unroll
  for (int i = 0; i < 8; ++i) ones[i] = (__fp16)1.0f;

  f32x4 accA[4], accB[4], acc5A, acc5B;
  #pragma unroll
  for (int t = 0; t < 4; ++t) {
    accA[t] = (f32x4){0.f, 0.f, 0.f, 0.f};
    accB[t] = (f32x4){0.f, 0.f, 0.f, 0.f};
  }
  acc5A = (f32x4){0.f, 0.f, 0.f, 0.f};
  acc5B = (f32x4){0.f, 0.f, 0.f, 0.f};

  for (int it = 0; it < NIT; ++it) {
    const int cur = it & 1;
    if (it + 1 < NIT) {    // write tile it+1 (regs loaded >=1 iter ago: free)
      #pragma unroll
      for (int i = 0; i < 4; ++i)
        *(float4*)((char*)&vbuf[cur ^ 1][0] + i * 4096 + tid * 16) = pB[i];
    }
    if (it + 2 < NIT) {    // issue loads for tile it+2 (full-iter cover)
      const char* srcb = hBp + (size_t)(it + 2) * 16384;
      #pragma unroll
      for (int i = 0; i < 4; ++i)
        pB[i] = *(const float4*)(srcb + i * 4096 + tid * 16);
    }
    unsigned short nkA0 = 0, nkA1 = 0, nkB0 = 0, nkB1 = 0;
    if (it + 1 < NIT) {
      nkA0 = mpA[(size_t)(it + 1) * 128];
      nkA1 = mpA[(size_t)(it + 1) * 128 + 64];
      nkB0 = mpB[(size_t)(it + 1) * 128];
      nkB1 = mpB[(size_t)(it + 1) * 128 + 64];
    }

    #pragma unroll
    for (int h = 0; h < 4; ++h) {              // 4 ksteps of 32 j
      const int jk = it * TJ + h * 32;
      uint4 e1u = *(const uint4*)((const char*)&ets[0][jk] + quad * 16);
      uint4 e2u = *(const uint4*)((const char*)&ets[1][jk] + quad * 16);
      const unsigned int mwA = (h < 2) ? (unsigned int)mkA0 : (unsigned int)mkA1;
      const unsigned int mwB = (h < 2) ? (unsigned int)mkB0 : (unsigned int)mkB1;
      const unsigned int mbA = (mwA >> (8 * (h & 1))) & 0xffu;
      const unsigned int mbB = (mwB >> (8 * (h & 1))) & 0xffu;
      const uint2 mAa = mlut[mbA & 15u];
      const uint2 mAb = mlut[mbA >> 4];
      const uint2 mBa = mlut[mbB & 15u];
      const uint2 mBb = mlut[mbB >> 4];
      union { unsigned int u[4]; f16x8 v8; } afA, afB;
      afA.u[0] = wmax(EpA2, EqA2, e1u.x, e2u.x) & mAa.x;
      afA.u[1] = wmax(EpA2, EqA2, e1u.y, e2u.y) & mAa.y;
      afA.u[2] = wmax(EpA2, EqA2, e1u.z, e2u.z) & mAb.x;
      afA.u[3] = wmax(EpA2, EqA2, e1u.w, e2u.w) & mAb.y;
      afB.u[0] = wmax(EpB2, EqB2, e1u.x, e2u.x) & mBa.x;
      afB.u[1] = wmax(EpB2, EqB2, e1u.y, e2u.y) & mBa.y;
      afB.u[2] = wmax(EpB2, EqB2, e1u.z, e2u.z) & mBb.x;
      afB.u[3] = wmax(EpB2, EqB2, e1u.w, e2u.w) & mBb.y;
      const f16x8 aA = afA.v8, aB = afB.v8;
      acc5A = __builtin_amdgcn_mfma_f32_16x16x32_f16(aA, ones, acc5A, 0, 0, 0);
      acc5B = __builtin_amdgcn_mfma_f32_16x16x32_f16(aB, ones, acc5B, 0, 0, 0);
      const __fp16* vb = &vbuf[cur][h * 2048];
      #pragma unroll
      for (int t = 0; t < 4; ++t) {
        f16x8 bf = *(const f16x8*)(vb + t * 512 + l * 8);
        accA[t] = __builtin_amdgcn_mfma_f32_16x16x32_f16(aA, bf, accA[t], 0, 0, 0);
        accB[t] = __builtin_amdgcn_mfma_f32_16x16x32_f16(aB, bf, accB[t], 0, 0, 0);
      }
    }
    mkA0 = nkA0; mkA1 = nkA1; mkB0 = nkB0; mkB1 = nkB1;
    __syncthreads();
  }

  // epilogue: per-wave direct write for both row-tiles
  float lrA[4], lrB[4];
  #pragma unroll
  for (int r = 0; r < 4; ++r) {
    lrA[r] = 1.f / acc5A[r];
    lrB[r] = 1.f / acc5B[r];
  }
  #pragma unroll
  for (int t = 0; t < 4; ++t) {
    const float bv = bias[head * 64 + t * 16 + c15];
    #pragma unroll
    for (int r = 0; r < 4; ++r) {
      {
        const int i = i0w + quad * 4 + r;
        float v = accA[t][r] * lrA[r] + bv;
        v = (v > 0.f) ? v : expm1f(v);          // elu
        g1[(size_t)(b * N_ + i) * 512 + head * 64 + t * 16 + c15] = (__fp16)v;
      }
      {
        const int i = i0w + 16 + quad * 4 + r;
        float v = accB[t][r] * lrB[r] + bv;
        v = (v > 0.f) ? v : expm1f(v);
        g1[(size_t)(b * N_ + i) * 512 + head * 64 + t * 16 + c15] = (__fp16)v;
      }
    }
  }
}

// ---------------------------------------------------------------------------
// ATT2: R7/R8 structure unchanged (factorized weights + depth-2 staging).
// 512 blocks of 32 rows x 64 cols; 8 waves = 2 rowg x 4 jq of 512; TJ=32.
// ---------------------------------------------------------------------------
__global__ __launch_bounds__(512, 4) void k_att2(
    const __fp16* __restrict__ hB, const float* __restrict__ s1,
    const __fp16* __restrict__ e1, const __fp16* __restrict__ e2,
    const float* __restrict__ pmx2,
    const unsigned short* __restrict__ mask2,
    const float* __restrict__ bias, float* __restrict__ out)
{
  constexpr int NRG = 2, NJQ = 4, JLEN = 512, TJ = 32, NIT = JLEN / TJ;
  constexpr int TILE = TJ * 64;                // 2048 f16 / slot (4 KB)

  __shared__ __fp16 vbuf[NJQ][2][TILE];        // 32 KB
  __shared__ __fp16 ets[2][N_];                // 8 KB
  __shared__ uint2 mlut[16];

  const int tid = threadIdx.x;
  const int w = tid >> 6, l = tid & 63;
  const int quad = l >> 4, c15 = l & 15;
  const int rowg = w % NRG, jq = w / NRG;
  const int tc = rowg * 64 + l;                // [0,128)

  int idx = blockIdx.x;
  const int ig = idx & 63; idx >>= 6;
  const int fs = idx & 1;
  const int b = idx >> 1;
  const int i0w = ig * 32 + rowg * 16;

  const float* s1p = s1 + (size_t)b * N_;
  const char* hBp = (const char*)(hB + (size_t)b * 64 * 4096 + fs * 2048);
  const unsigned short* mp = mask2 + ((size_t)(b * 128 + (i0w >> 4)) * 32) * 64 + l;

  const int jbase = jq * JLEN;

  if (tid < 16) {
    unsigned int v = tid;
    mlut[tid] = (uint2){ ((v & 1u) ? 0xffffu : 0u) | ((v & 2u) ? 0xffff0000u : 0u),
                         ((v & 4u) ? 0xffffu : 0u) | ((v & 8u) ? 0xffff0000u : 0u) };
  }

  float4 pA0 = *(const float4*)(hBp + (size_t)(jbase >> 5) * 8192 + tc * 16);
  float4 pA1 = *(const float4*)(hBp + (size_t)(jbase >> 5) * 8192 + (tc + 128) * 16);
  float4 pB0 = *(const float4*)(hBp + (size_t)((jbase + TJ) >> 5) * 8192 + tc * 16);
  float4 pB1 = *(const float4*)(hBp + (size_t)((jbase + TJ) >> 5) * 8192 + (tc + 128) * 16);
  unsigned short mk = mp[(size_t)(jbase >> 6) * 64];

  {
    const int half = tid >> 8, off = (tid & 255) * 8;
    const __fp16* src = (half ? e2 : e1) + (size_t)b * N_ + off;
    *(f16x8*)&ets[half][off] = *(const f16x8*)src;
  }

  const float s1v = s1p[i0w + c15];
  float s2m;
  {
    const float* pm = pmx2 + (size_t)b * 128;
    float tmx = fmaxf(pm[l], pm[l + 64]);
    #pragma unroll
    for (int off = 1; off < 64; off <<= 1)
      tmx = fmaxf(tmx, __shfl_xor(tmx, off, 64));
    s2m = tmx;
  }
  *(float4*)((char*)&vbuf[jq][0][0] + tc * 16) = pA0;
  *(float4*)((char*)&vbuf[jq][0][0] + (tc + 128) * 16) = pA1;
  __syncthreads();

  const float zm = s1v + s2m;
  const float m = fmaxf(zm, SLOPE_ * zm);
  const float Ep = __builtin_amdgcn_exp2f(s1v - m);
  const float Eq = __builtin_amdgcn_exp2f(SLOPE_ * s1v - m);
  const f16x2 Ep2 = __builtin_amdgcn_cvt_pkrtz(Ep, Ep);
  const f16x2 Eq2 = __builtin_amdgcn_cvt_pkrtz(Eq, Eq);

  f16x8 ones;
  #pragma unroll
  for (int i = 0; i < 8; ++i) ones[i] = (__fp16)1.0f;

  f32x4 acc[4], acc5;
  #pragma unroll
  for (int t = 0; t < 4; ++t) acc[t] = (f32x4){0.f, 0.f, 0.f, 0.f};
  acc5 = (f32x4){0.f, 0.f, 0.f, 0.f};

  for (int it = 0; it < NIT; ++it) {
    const int cur = it & 1;
    const int j0 = jbase + it * TJ;
    if (it + 1 < NIT) {
      *(float4*)((char*)&vbuf[jq][cur ^ 1][0] + tc * 16) = pB0;
      *(float4*)((char*)&vbuf[jq][cur ^ 1][0] + (tc + 128) * 16) = pB1;
    }
    if (it + 2 < NIT) {
      pB0 = *(const float4*)(hBp + (size_t)((j0 + 2 * TJ) >> 5) * 8192 + tc * 16);
      pB1 = *(const float4*)(hBp + (size_t)((j0 + 2 * TJ) >> 5) * 8192 + (tc + 128) * 16);
    }
    unsigned short nk = 0;
    if (it + 1 < NIT) nk = mp[(size_t)((j0 + TJ) >> 6) * 64];

    uint4 e1u = *(const uint4*)((const char*)&ets[0][j0] + quad * 16);
    uint4 e2u = *(const uint4*)((const char*)&ets[1][j0] + quad * 16);
    const unsigned int mbyte = ((unsigned int)mk >> (8 * ((j0 >> 5) & 1))) & 0xffu;
    const uint2 mA = mlut[mbyte & 15u];
    const uint2 mB = mlut[mbyte >> 4];
    union { unsigned int u[4]; f16x8 v8; } af;
    af.u[0] = wmax(Ep2, Eq2, e1u.x, e2u.x) & mA.x;
    af.u[1] = wmax(Ep2, Eq2, e1u.y, e2u.y) & mA.y;
    af.u[2] = wmax(Ep2, Eq2, e1u.z, e2u.z) & mB.x;
    af.u[3] = wmax(Ep2, Eq2, e1u.w, e2u.w) & mB.y;
    const f16x8 a = af.v8;
    acc5 = __builtin_amdgcn_mfma_f32_16x16x32_f16(a, ones, acc5, 0, 0, 0);
    const __fp16* vb = &vbuf[jq][cur][0];
    #pragma unroll
    for (int t = 0; t < 4; ++t) {
      f16x8 bf = *(const f16x8*)(vb + t * 512 + l * 8);
      acc[t] = __builtin_amdgcn_mfma_f32_16x16x32_f16(a, bf, acc[t], 0, 0, 0);
    }
    mk = nk;
    __syncthreads();
  }

  // combine across 4 j-chunks (overlay: pacc 24 KB in vbuf, pls after it)
  auto pacc = (float(*)[NRG][16][64])(&vbuf[0][0][0]);
  auto pls  = (float(*)[NRG][16])((char*)&vbuf[0][0][0] + 24576);
  if (jq > 0) {
    #pragma unroll
    for (int t = 0; t < 4; ++t)
      #pragma unroll
      for (int r = 0; r < 4; ++r)
        pacc[jq - 1][rowg][quad * 4 + r][t * 16 + c15] = acc[t][r];
    if (c15 == 0) {
      #pragma unroll
      for (int r = 0; r < 4; ++r) pls[jq - 1][rowg][quad * 4 + r] = acc5[r];
    }
  }
  __syncthreads();
  if (jq == 0) {
    float Lrow[4];
    #pragma unroll
    for (int r = 0; r < 4; ++r) Lrow[r] = acc5[r];
    #pragma unroll
    for (int q = 0; q < NJQ - 1; ++q) {
      #pragma unroll
      for (int t = 0; t < 4; ++t)
        #pragma unroll
        for (int r = 0; r < 4; ++r)
          acc[t][r] += pacc[q][rowg][quad * 4 + r][t * 16 + c15];
      #pragma unroll
      for (int r = 0; r < 4; ++r) Lrow[r] += pls[q][rowg][quad * 4 + r];
    }
    float lr[4];
    #pragma unroll
    for (int r = 0; r < 4; ++r) lr[r] = 1.f / Lrow[r];
    #pragma unroll
    for (int t = 0; t < 4; ++t) {
      const float bv = bias[fs * 64 + t * 16 + c15];
      #pragma unroll
      for (int r = 0; r < 4; ++r) {
        const int i = i0w + quad * 4 + r;
        float v = acc[t][r] * lr[r] + bv;
        out[(size_t)(b * N_ + i) * 128 + fs * 64 + t * 16 + c15] = fmaxf(v, 0.f);
      }
    }
  }
}

// ---------------------------------------------------------------------------
extern "C" void kernel_launch(void* const* d_in, const int* in_sizes, int n_in,
                              void* d_out, int out_size, void* d_ws, size_t ws_size,
                              hipStream_t stream) {
  const float* x   = (const float*)d_in[0];
  const int*   adj = (const int*)d_in[1];
  const float* Wh  = (const float*)d_in[2];
  const float* ah  = (const float*)d_in[3];
  const float* bh  = (const float*)d_in[4];
  const float* Wo  = (const float*)d_in[5];
  const float* ao  = (const float*)d_in[6];
  const float* bo  = (const float*)d_in[7];
  float* out = (float*)d_out;

  float* ws   = (float*)d_ws;
  float* s1h  = ws;                                   // B*8*N
  float* s2h  = s1h  + (size_t)B_ * NHEADS_ * N_;     // (unused; keeps layout)
  float* s1o  = s2h  + (size_t)B_ * NHEADS_ * N_;     // B*N
  float* s2o  = s1o  + (size_t)B_ * N_;               // (unused; keeps layout)
  __fp16* g1  = (__fp16*)(s2o + (size_t)B_ * N_);     // B*N*512 f16 (8 MB)
  __fp16* hB1 = g1  + (size_t)B_ * N_ * 512;          // 8 MB
  __fp16* hB2 = hB1 + (size_t)B_ * NHEADS_ * N_ * 64; // 2 MB
  __fp16* WhB = hB2 + (size_t)B_ * N_ * 128;          // 256 KB
  __fp16* WoB = WhB + (size_t)8 * 256 * 64;           // 128 KB
  unsigned short* mask2 = (unsigned short*)(WoB + (size_t)512 * 128); // 2 MB
  __fp16* e1h = (__fp16*)(mask2 + (size_t)B_ * 128 * 32 * 64);  // 128 KB
  __fp16* e2h = e1h + (size_t)B_ * NHEADS_ * N_;                // 128 KB
  __fp16* e1o = e2h + (size_t)B_ * NHEADS_ * N_;                // 16 KB
  __fp16* e2o = e1o + (size_t)B_ * N_;                          // 16 KB
  float* pmx1 = (float*)(e2o + (size_t)B_ * N_);                // 16 KB
  float* pmx2 = pmx1 + (size_t)B_ * NHEADS_ * 128;              // 2 KB

  k_prep<<<4192, 256, 0, stream>>>(adj, mask2, Wh, WhB, Wo, WoB);
  k_gemm1<<<B_ * (N_ / 16), 256, 0, stream>>>(x, WhB, ah, hB1, s1h, e1h, e2h, pmx1);
  k_att1<<<B_ * NHEADS_ * (N_ / 128), 256, 0, stream>>>(
      hB1, s1h, e1h, e2h, pmx1, mask2, bh, g1);
  k_gemm2<<<B_ * (N_ / 16), 256, 0, stream>>>(g1, WoB, ao, hB2, s1o, e1o, e2o, pmx2);
  k_att2<<<B_ * 2 * (N_ / 32), 512, 0, stream>>>(
      hB2, s1o, e1o, e2o, pmx2, mask2, bo, out);
}

// Round 10
// 182.716 us; speedup vs baseline: 1.1508x; 1.1508x over previous
//
#include <hip/hip_runtime.h>

constexpr int B_ = 4;
constexpr int N_ = 2048;
constexpr int NFEAT_ = 256;
constexpr int NHEADS_ = 8;
constexpr float SLOPE_ = 0.1f;
constexpr float L2E = 1.4426950408889634f;   // log2(e)

typedef __attribute__((ext_vector_type(8))) __fp16 f16x8;
typedef __attribute__((ext_vector_type(4))) __fp16 f16x4;
typedef __attribute__((ext_vector_type(2))) __fp16 f16x2;
typedef __attribute__((ext_vector_type(4))) float f32x4;

__device__ __forceinline__ f16x8 pack8(const float* v) {
  union { f16x2 h2[4]; f16x8 h8; } u;
  u.h2[0] = __builtin_amdgcn_cvt_pkrtz(v[0], v[1]);
  u.h2[1] = __builtin_amdgcn_cvt_pkrtz(v[2], v[3]);
  u.h2[2] = __builtin_amdgcn_cvt_pkrtz(v[4], v[5]);
  u.h2[3] = __builtin_amdgcn_cvt_pkrtz(v[6], v[7]);
  return u.h8;
}
__device__ __forceinline__ f16x4 pack4(float a, float b, float c, float d) {
  union { f16x2 h2[2]; f16x4 h4; } u;
  u.h2[0] = __builtin_amdgcn_cvt_pkrtz(a, b);
  u.h2[1] = __builtin_amdgcn_cvt_pkrtz(c, d);
  return u.h4;
}

// weight pair = max(Ep*E1pair, Eq*E2pair) in packed f16 (exp2 is monotone, so
// exp2(max(t0,t1)) == max(exp2 t0, exp2 t1); both branches factor row x col).
__device__ __forceinline__ unsigned int wmax(f16x2 Ep2, f16x2 Eq2,
                                             unsigned int e1p, unsigned int e2p) {
  f16x2 ea, eb;
  __builtin_memcpy(&ea, &e1p, 4);
  __builtin_memcpy(&eb, &e2p, 4);
  f16x2 a, b, c;
  asm("v_pk_mul_f16 %0, %1, %2" : "=v"(a) : "v"(Ep2), "v"(ea));
  asm("v_pk_mul_f16 %0, %1, %2" : "=v"(b) : "v"(Eq2), "v"(eb));
  asm("v_pk_max_f16 %0, %1, %2" : "=v"(c) : "v"(a), "v"(b));
  unsigned int r;
  __builtin_memcpy(&r, &c, 4);
  return r;
}

// ---------------------------------------------------------------------------
// Fused prep: blocks [0,4096) packmask; [4096,4160) prepWh; [4160,4192) prepWo
// ---------------------------------------------------------------------------
__global__ __launch_bounds__(256) void k_prep(
    const int* __restrict__ adj, unsigned short* __restrict__ mask2,
    const float* __restrict__ Wh, __fp16* __restrict__ WhB,
    const float* __restrict__ Wo, __fp16* __restrict__ WoB)
{
  const int bid = blockIdx.x;
  const int l = threadIdx.x & 63;
  if (bid < 4096) {
    const size_t gw = ((size_t)bid * 256 + threadIdx.x) >> 6;
    const int jt = (int)(gw & 31);
    const int ig16 = (int)((gw >> 5) & 127);
    const int b = (int)(gw >> 12);
    const int q = l >> 4, c15 = l & 15;
    const int* base = adj + ((size_t)b * N_ + ig16 * 16) * N_ + jt * 64 + l;
    unsigned int msk = 0;
    #pragma unroll
    for (int r = 0; r < 16; ++r) {
      int a = base[(size_t)r * N_];
      unsigned long long bal = __ballot(a > 0);
      unsigned int v = (unsigned int)((bal >> (q * 8)) & 0xffull)
                     | ((unsigned int)((bal >> (q * 8 + 32)) & 0xffull) << 8);
      if (r == c15) msk = v;
    }
    mask2[gw * 64 + l] = (unsigned short)msk;
  } else if (bid < 4160) {
    int s = (int)(((bid - 4096) * 256 + threadIdx.x) >> 6);   // 0..255
    int h = s >> 5, ks = (s >> 2) & 7, ft = s & 3;
    const float* src = Wh + ((size_t)h * 256 + ks * 32 + (l >> 4) * 8) * 64 + ft * 16 + (l & 15);
    float v[8];
    #pragma unroll
    for (int j = 0; j < 8; ++j) v[j] = src[(size_t)j * 64];
    *(f16x8*)(WhB + (size_t)s * 512 + l * 8) = pack8(v);
  } else {
    int s = (int)(((bid - 4160) * 256 + threadIdx.x) >> 6);   // 0..127
    int ks = s >> 3, ft = s & 7;
    const float* src = Wo + ((size_t)ks * 32 + (l >> 4) * 8) * 128 + ft * 16 + (l & 15);
    float v[8];
    #pragma unroll
    for (int j = 0; j < 8; ++j) v[j] = src[(size_t)j * 128];
    *(f16x8*)(WoB + (size_t)s * 512 + l * 8) = pack8(v);
  }
}

// ---------------------------------------------------------------------------
// GEMM1 (MFMA): block = 16 n-rows x ALL 512 f (8 heads), 256 thr = 4 waves.
// Epilogue emits exp2 column tables e1h/e2h + per-(block,head) partial max
// (plain store, NO atomics).
// ---------------------------------------------------------------------------
__global__ __launch_bounds__(256, 4) void k_gemm1(
    const float* __restrict__ x, const __fp16* __restrict__ WhB,
    const float* __restrict__ ah,
    __fp16* __restrict__ hB1, float* __restrict__ s1h,
    __fp16* __restrict__ e1h, __fp16* __restrict__ e2h,
    float* __restrict__ pmx1)
{
  constexpr int XP = 264;
  __shared__ __fp16 xs[16 * XP];
  __shared__ __fp16 hT[512 * 16];

  const int t = threadIdx.x;
  const int bid = blockIdx.x;
  const int b = bid >> 7;
  const int n0 = (bid & 127) * 16;

  {  // stage x -> f16
    int r = t >> 4, k0 = (t & 15) * 16;
    const float* src = x + ((size_t)(b * N_) + n0 + r) * NFEAT_ + k0;
    float v0[8], v1[8];
    *(float4*)&v0[0] = *(const float4*)(src);
    *(float4*)&v0[4] = *(const float4*)(src + 4);
    *(float4*)&v1[0] = *(const float4*)(src + 8);
    *(float4*)&v1[4] = *(const float4*)(src + 12);
    *(f16x8*)&xs[r * XP + k0] = pack8(v0);
    *(f16x8*)&xs[r * XP + k0 + 8] = pack8(v1);
  }
  __syncthreads();

  const int w = t >> 6, l = t & 63;
  const int quad = l >> 4, c15 = l & 15;

  f32x4 acc[8];
  #pragma unroll
  for (int i = 0; i < 8; ++i) acc[i] = (f32x4){0.f, 0.f, 0.f, 0.f};

  for (int ks = 0; ks < 8; ++ks) {
    f16x8 af = *(const f16x8*)&xs[c15 * XP + ks * 32 + quad * 8];
    #pragma unroll
    for (int tt = 0; tt < 8; ++tt) {
      int hl = tt >> 2, ft = tt & 3;
      f16x8 bf = *(const f16x8*)(WhB +
          ((((size_t)(2 * w + hl) * 8 + ks) * 4 + ft) * 512) + l * 8);
      acc[tt] = __builtin_amdgcn_mfma_f32_16x16x32_f16(af, bf, acc[tt], 0, 0, 0);
    }
  }

  #pragma unroll
  for (int hl = 0; hl < 2; ++hl) {
    int head = 2 * w + hl;
    float a1v[4], a2v[4];
    #pragma unroll
    for (int ft = 0; ft < 4; ++ft) {
      a1v[ft] = ah[head * 128 + ft * 16 + c15] * L2E;
      a2v[ft] = ah[head * 128 + 64 + ft * 16 + c15] * L2E;
    }
    float hmax = -1e30f;
    #pragma unroll
    for (int r = 0; r < 4; ++r) {
      float v1 = 0.f, v2 = 0.f;
      #pragma unroll
      for (int ft = 0; ft < 4; ++ft) {
        v1 = fmaf(acc[hl * 4 + ft][r], a1v[ft], v1);
        v2 = fmaf(acc[hl * 4 + ft][r], a2v[ft], v2);
      }
      #pragma unroll
      for (int off = 1; off < 16; off <<= 1) {
        v1 += __shfl_xor(v1, off, 64);
        v2 += __shfl_xor(v2, off, 64);
      }
      if (c15 == 0) {
        const size_t nn = (size_t)(b * NHEADS_ + head) * N_ + n0 + quad * 4 + r;
        s1h[nn] = v1;
        e1h[nn] = (__fp16)__builtin_amdgcn_exp2f(v2);
        e2h[nn] = (__fp16)__builtin_amdgcn_exp2f(SLOPE_ * v2);
      }
      hmax = fmaxf(hmax, v2);
    }
    hmax = fmaxf(hmax, __shfl_xor(hmax, 16, 64));
    hmax = fmaxf(hmax, __shfl_xor(hmax, 32, 64));
    if (l == 0)
      pmx1[(size_t)(b * NHEADS_ + head) * 128 + (n0 >> 4)] = hmax;
  }

  #pragma unroll
  for (int tt = 0; tt < 8; ++tt) {
    int f = (2 * w + (tt >> 2)) * 64 + (tt & 3) * 16 + c15;
    *(f16x4*)&hT[f * 16 + quad * 4] =
        pack4(acc[tt][0], acc[tt][1], acc[tt][2], acc[tt][3]);
  }
  __syncthreads();

  const int base_oct = (n0 >> 3) & 3;
  #pragma unroll
  for (int q = 0; q < 4; ++q) {
    int s = t + q * 256;
    int c15v = s & 15, oct = (s >> 4) & 1, ft = (s >> 5) & 3, head = s >> 7;
    f16x8 v = *(const f16x8*)&hT[(head * 64 + ft * 16 + c15v) * 16 + oct * 8];
    int lane0 = (base_oct + oct) * 16 + c15v;
    *(f16x8*)(hB1 +
        ((((size_t)(b * NHEADS_ + head) * 64 + (n0 >> 5)) * 4 + ft) * 512) + lane0 * 8) = v;
  }
}

// ---------------------------------------------------------------------------
// GEMM2 (MFMA): block = 16 n-rows x 128 f, 256 thr = 4 waves.
// Epilogue emits e1o/e2o tables + per-block partial max (plain store).
// ---------------------------------------------------------------------------
__global__ __launch_bounds__(256, 4) void k_gemm2(
    const __fp16* __restrict__ g1, const __fp16* __restrict__ WoB,
    const float* __restrict__ ao,
    __fp16* __restrict__ hB2, float* __restrict__ s1o,
    __fp16* __restrict__ e1o, __fp16* __restrict__ e2o,
    float* __restrict__ pmx2)
{
  constexpr int GP = 520;
  __shared__ __fp16 gs[16 * GP];
  __shared__ __fp16 hT[128 * 16];
  __shared__ float sd1[4][16], sd2[4][16];

  const int t = threadIdx.x;
  const int bid = blockIdx.x;
  const int b = bid >> 7;
  const int n0 = (bid & 127) * 16;

  {
    int r = t >> 4, k0 = (t & 15) * 32;
    const __fp16* src = g1 + ((size_t)(b * N_) + n0 + r) * 512 + k0;
    #pragma unroll
    for (int i = 0; i < 4; ++i)
      *(f16x8*)&gs[r * GP + k0 + i * 8] = *(const f16x8*)(src + i * 8);
  }
  __syncthreads();

  const int w = t >> 6, l = t & 63;
  const int quad = l >> 4, c15 = l & 15;

  f32x4 acc[2];
  acc[0] = (f32x4){0.f, 0.f, 0.f, 0.f};
  acc[1] = (f32x4){0.f, 0.f, 0.f, 0.f};

  for (int ks = 0; ks < 16; ++ks) {
    f16x8 af = *(const f16x8*)&gs[c15 * GP + ks * 32 + quad * 8];
    #pragma unroll
    for (int tt = 0; tt < 2; ++tt) {
      int ft = 2 * w + tt;
      f16x8 bf = *(const f16x8*)(WoB + (((size_t)ks * 8 + ft) * 512) + l * 8);
      acc[tt] = __builtin_amdgcn_mfma_f32_16x16x32_f16(af, bf, acc[tt], 0, 0, 0);
    }
  }

  {
    float a1v[2], a2v[2];
    #pragma unroll
    for (int tt = 0; tt < 2; ++tt) {
      int f = (2 * w + tt) * 16 + c15;
      a1v[tt] = ao[f] * L2E;
      a2v[tt] = ao[128 + f] * L2E;
    }
    #pragma unroll
    for (int r = 0; r < 4; ++r) {
      float v1 = acc[0][r] * a1v[0] + acc[1][r] * a1v[1];
      float v2 = acc[0][r] * a2v[0] + acc[1][r] * a2v[1];
      #pragma unroll
      for (int off = 1; off < 16; off <<= 1) {
        v1 += __shfl_xor(v1, off, 64);
        v2 += __shfl_xor(v2, off, 64);
      }
      if (c15 == 0) { sd1[w][quad * 4 + r] = v1; sd2[w][quad * 4 + r] = v2; }
    }
  }

  #pragma unroll
  for (int tt = 0; tt < 2; ++tt) {
    int f = (2 * w + tt) * 16 + c15;
    *(f16x4*)&hT[f * 16 + quad * 4] =
        pack4(acc[tt][0], acc[tt][1], acc[tt][2], acc[tt][3]);
  }
  __syncthreads();

  if (t < 16)
    s1o[(size_t)b * N_ + n0 + t] = sd1[0][t] + sd1[1][t] + sd1[2][t] + sd1[3][t];
  else if (t < 32) {
    int rr = t - 16;
    float v = sd2[0][rr] + sd2[1][rr] + sd2[2][rr] + sd2[3][rr];
    e1o[(size_t)b * N_ + n0 + rr] = (__fp16)__builtin_amdgcn_exp2f(v);
    e2o[(size_t)b * N_ + n0 + rr] = (__fp16)__builtin_amdgcn_exp2f(SLOPE_ * v);
    float hm = v;
    hm = fmaxf(hm, __shfl_xor(hm, 1, 64));
    hm = fmaxf(hm, __shfl_xor(hm, 2, 64));
    hm = fmaxf(hm, __shfl_xor(hm, 4, 64));
    hm = fmaxf(hm, __shfl_xor(hm, 8, 64));
    if (rr == 0) pmx2[(size_t)b * 128 + (n0 >> 4)] = hm;
  }

  {
    int c15v = t & 15, oct = (t >> 4) & 1, ft = t >> 5;
    f16x8 v = *(const f16x8*)&hT[(ft * 16 + c15v) * 16 + oct * 8];
    int base_oct = (n0 >> 3) & 3;
    int lane0 = (base_oct + oct) * 16 + c15v;
    *(f16x8*)(hB2 +
        (((size_t)(b * 64 + (n0 >> 5)) * 8 + ft) * 512) + lane0 * 8) = v;
  }
}

// ---------------------------------------------------------------------------
// ATT1: revert to the R8 best structure (512 thr, 8 waves x 16 rows, shared
// TJ=128 dbuf tile, depth-2 reg staging — 33.5 us), with ONE change: the E
// tables are read DIRECT from global (L2-hot, 16 B/wave/h-step, batched 4
// h-steps ahead into 8 uint4 regs) instead of LDS. Cuts per-h-step LDS b128
// reads 6 -> 4 on an LDS-throughput-bound kernel, deletes ets staging.
// R9's 2-tile/wave variant is abandoned: it halves occupancy (4096 wave-jobs
// at 16 rows = exactly 4 waves/SIMD; 32-row waves -> 2/SIMD) and spilled.
// ---------------------------------------------------------------------------
__global__ __launch_bounds__(512, 4) void k_att1(
    const __fp16* __restrict__ hB, const float* __restrict__ s1,
    const __fp16* __restrict__ e1, const __fp16* __restrict__ e2,
    const float* __restrict__ pmx1,
    const unsigned short* __restrict__ mask2,
    const float* __restrict__ bias, __fp16* __restrict__ g1)
{
  constexpr int TJ = 128, NIT = N_ / TJ;       // 16 iterations
  constexpr int TILE = TJ * 64;                // 8192 f16 = 16 KB / slot

  __shared__ __fp16 vbuf[2][TILE];             // 32 KB (shared by all 8 waves)
  __shared__ uint2 mlut[16];                   // nibble -> 2 packed pair masks

  const int tid = threadIdx.x;
  const int w = tid >> 6, l = tid & 63;
  const int quad = l >> 4, c15 = l & 15;

  int idx = blockIdx.x;
  const int ig = idx & 15; idx >>= 4;          // N/128 = 16 row-tiles
  const int head = idx & 7;
  const int b = idx >> 3;
  const int i0w = ig * 128 + w * 16;           // wave's 16-row group
  const int bh = b * NHEADS_ + head;

  const float* s1p = s1 + (size_t)bh * N_;
  const char* hBp = (const char*)(hB + (size_t)bh * (N_ / 32) * 2048);
  const unsigned short* mp = mask2 + ((size_t)(b * 128 + (i0w >> 4)) * 32) * 64 + l;
  const __fp16* e1g = e1 + (size_t)bh * N_ + quad * 8;   // quad-sliced tables
  const __fp16* e2g = e2 + (size_t)bh * N_ + quad * 8;

  if (tid < 16) {
    unsigned int v = tid;
    mlut[tid] = (uint2){ ((v & 1u) ? 0xffffu : 0u) | ((v & 2u) ? 0xffff0000u : 0u),
                         ((v & 4u) ? 0xffffu : 0u) | ((v & 8u) ? 0xffff0000u : 0u) };
  }

  // depth-2 prologue: tiles 0 and 1 in flight (16 KB each, 2 float4/thread)
  float4 pA0 = *(const float4*)(hBp + tid * 16);
  float4 pA1 = *(const float4*)(hBp + 8192 + tid * 16);
  float4 pB0 = *(const float4*)(hBp + 16384 + tid * 16);
  float4 pB1 = *(const float4*)(hBp + 16384 + 8192 + tid * 16);
  unsigned short mk0 = mp[0];
  unsigned short mk1 = mp[64];

  const float s1v = s1p[i0w + c15];
  // row max of s2 from the 128 partials (every wave redundantly)
  float s2m;
  {
    const float* pm = pmx1 + (size_t)bh * 128;
    float tmx = fmaxf(pm[l], pm[l + 64]);
    #pragma unroll
    for (int off = 1; off < 64; off <<= 1)
      tmx = fmaxf(tmx, __shfl_xor(tmx, off, 64));
    s2m = tmx;
  }
  // write tile 0 (vmcnt on pA elapsed under the work above)
  *(float4*)((char*)&vbuf[0][0] + tid * 16) = pA0;
  *(float4*)((char*)&vbuf[0][0] + 8192 + tid * 16) = pA1;
  __syncthreads();

  const float zm = s1v + s2m;
  const float m = fmaxf(zm, SLOPE_ * zm);      // exact unmasked row max
  const float Ep = __builtin_amdgcn_exp2f(s1v - m);
  const float Eq = __builtin_amdgcn_exp2f(SLOPE_ * s1v - m);
  const f16x2 Ep2 = __builtin_amdgcn_cvt_pkrtz(Ep, Ep);
  const f16x2 Eq2 = __builtin_amdgcn_cvt_pkrtz(Eq, Eq);

  f16x8 ones;
  #pragma unroll
  for (int i = 0; i < 8; ++i) ones[i] = (__fp16)1.0f;

  f32x4 acc[4], acc5;
  #pragma unroll
  for (int t = 0; t < 4; ++t) acc[t] = (f32x4){0.f, 0.f, 0.f, 0.f};
  acc5 = (f32x4){0.f, 0.f, 0.f, 0.f};

  for (int it = 0; it < NIT; ++it) {
    const int cur = it & 1;
    // E-table loads for this iteration (global; L2-hot; latency hidden under
    // the vbuf writes + prefetch issues below)
    uint4 e1i[4], e2i[4];
    #pragma unroll
    for (int h = 0; h < 4; ++h) {
      e1i[h] = *(const uint4*)(e1g + it * TJ + h * 32);
      e2i[h] = *(const uint4*)(e2g + it * TJ + h * 32);
    }
    if (it + 1 < NIT) {    // write tile it+1 (regs loaded >=1 iter ago: free)
      *(float4*)((char*)&vbuf[cur ^ 1][0] + tid * 16) = pB0;
      *(float4*)((char*)&vbuf[cur ^ 1][0] + 8192 + tid * 16) = pB1;
    }
    if (it + 2 < NIT) {    // issue loads for tile it+2 (full-iter cover)
      const char* srcb = hBp + (size_t)(it + 2) * 16384;
      pB0 = *(const float4*)(srcb + tid * 16);
      pB1 = *(const float4*)(srcb + 8192 + tid * 16);
    }
    unsigned short nk0 = 0, nk1 = 0;
    if (it + 1 < NIT) {
      nk0 = mp[(size_t)(it + 1) * 128];
      nk1 = mp[(size_t)(it + 1) * 128 + 64];
    }

    #pragma unroll
    for (int h = 0; h < 4; ++h) {              // 4 ksteps of 32 j
      const unsigned int mword = (h < 2) ? (unsigned int)mk0 : (unsigned int)mk1;
      const unsigned int mbyte = (mword >> (8 * (h & 1))) & 0xffu;
      const uint2 mA = mlut[mbyte & 15u];
      const uint2 mB = mlut[mbyte >> 4];
      union { unsigned int u[4]; f16x8 v8; } af;
      af.u[0] = wmax(Ep2, Eq2, e1i[h].x, e2i[h].x) & mA.x;
      af.u[1] = wmax(Ep2, Eq2, e1i[h].y, e2i[h].y) & mA.y;
      af.u[2] = wmax(Ep2, Eq2, e1i[h].z, e2i[h].z) & mB.x;
      af.u[3] = wmax(Ep2, Eq2, e1i[h].w, e2i[h].w) & mB.y;
      const f16x8 a = af.v8;
      acc5 = __builtin_amdgcn_mfma_f32_16x16x32_f16(a, ones, acc5, 0, 0, 0);
      const __fp16* vb = &vbuf[cur][h * 2048];
      #pragma unroll
      for (int t = 0; t < 4; ++t) {
        f16x8 bf = *(const f16x8*)(vb + t * 512 + l * 8);
        acc[t] = __builtin_amdgcn_mfma_f32_16x16x32_f16(a, bf, acc[t], 0, 0, 0);
      }
    }
    mk0 = nk0; mk1 = nk1;
    __syncthreads();
  }

  // epilogue: per-wave direct write (acc5 is the full-row denominator)
  float lr[4];
  #pragma unroll
  for (int r = 0; r < 4; ++r) lr[r] = 1.f / acc5[r];
  #pragma unroll
  for (int t = 0; t < 4; ++t) {
    const float bv = bias[head * 64 + t * 16 + c15];
    #pragma unroll
    for (int r = 0; r < 4; ++r) {
      const int i = i0w + quad * 4 + r;
      float v = acc[t][r] * lr[r] + bv;
      v = (v > 0.f) ? v : expm1f(v);            // elu
      g1[(size_t)(b * N_ + i) * 512 + head * 64 + t * 16 + c15] = (__fp16)v;
    }
  }
}

// ---------------------------------------------------------------------------
// ATT2: R7/R8 structure unchanged (factorized weights + depth-2 staging).
// 512 blocks of 32 rows x 64 cols; 8 waves = 2 rowg x 4 jq of 512; TJ=32.
// ---------------------------------------------------------------------------
__global__ __launch_bounds__(512, 4) void k_att2(
    const __fp16* __restrict__ hB, const float* __restrict__ s1,
    const __fp16* __restrict__ e1, const __fp16* __restrict__ e2,
    const float* __restrict__ pmx2,
    const unsigned short* __restrict__ mask2,
    const float* __restrict__ bias, float* __restrict__ out)
{
  constexpr int NRG = 2, NJQ = 4, JLEN = 512, TJ = 32, NIT = JLEN / TJ;
  constexpr int TILE = TJ * 64;                // 2048 f16 / slot (4 KB)

  __shared__ __fp16 vbuf[NJQ][2][TILE];        // 32 KB
  __shared__ __fp16 ets[2][N_];                // 8 KB
  __shared__ uint2 mlut[16];

  const int tid = threadIdx.x;
  const int w = tid >> 6, l = tid & 63;
  const int quad = l >> 4, c15 = l & 15;
  const int rowg = w % NRG, jq = w / NRG;
  const int tc = rowg * 64 + l;                // [0,128)

  int idx = blockIdx.x;
  const int ig = idx & 63; idx >>= 6;
  const int fs = idx & 1;
  const int b = idx >> 1;
  const int i0w = ig * 32 + rowg * 16;

  const float* s1p = s1 + (size_t)b * N_;
  const char* hBp = (const char*)(hB + (size_t)b * 64 * 4096 + fs * 2048);
  const unsigned short* mp = mask2 + ((size_t)(b * 128 + (i0w >> 4)) * 32) * 64 + l;

  const int jbase = jq * JLEN;

  if (tid < 16) {
    unsigned int v = tid;
    mlut[tid] = (uint2){ ((v & 1u) ? 0xffffu : 0u) | ((v & 2u) ? 0xffff0000u : 0u),
                         ((v & 4u) ? 0xffffu : 0u) | ((v & 8u) ? 0xffff0000u : 0u) };
  }

  float4 pA0 = *(const float4*)(hBp + (size_t)(jbase >> 5) * 8192 + tc * 16);
  float4 pA1 = *(const float4*)(hBp + (size_t)(jbase >> 5) * 8192 + (tc + 128) * 16);
  float4 pB0 = *(const float4*)(hBp + (size_t)((jbase + TJ) >> 5) * 8192 + tc * 16);
  float4 pB1 = *(const float4*)(hBp + (size_t)((jbase + TJ) >> 5) * 8192 + (tc + 128) * 16);
  unsigned short mk = mp[(size_t)(jbase >> 6) * 64];

  {
    const int half = tid >> 8, off = (tid & 255) * 8;
    const __fp16* src = (half ? e2 : e1) + (size_t)b * N_ + off;
    *(f16x8*)&ets[half][off] = *(const f16x8*)src;
  }

  const float s1v = s1p[i0w + c15];
  float s2m;
  {
    const float* pm = pmx2 + (size_t)b * 128;
    float tmx = fmaxf(pm[l], pm[l + 64]);
    #pragma unroll
    for (int off = 1; off < 64; off <<= 1)
      tmx = fmaxf(tmx, __shfl_xor(tmx, off, 64));
    s2m = tmx;
  }
  *(float4*)((char*)&vbuf[jq][0][0] + tc * 16) = pA0;
  *(float4*)((char*)&vbuf[jq][0][0] + (tc + 128) * 16) = pA1;
  __syncthreads();

  const float zm = s1v + s2m;
  const float m = fmaxf(zm, SLOPE_ * zm);
  const float Ep = __builtin_amdgcn_exp2f(s1v - m);
  const float Eq = __builtin_amdgcn_exp2f(SLOPE_ * s1v - m);
  const f16x2 Ep2 = __builtin_amdgcn_cvt_pkrtz(Ep, Ep);
  const f16x2 Eq2 = __builtin_amdgcn_cvt_pkrtz(Eq, Eq);

  f16x8 ones;
  #pragma unroll
  for (int i = 0; i < 8; ++i) ones[i] = (__fp16)1.0f;

  f32x4 acc[4], acc5;
  #pragma unroll
  for (int t = 0; t < 4; ++t) acc[t] = (f32x4){0.f, 0.f, 0.f, 0.f};
  acc5 = (f32x4){0.f, 0.f, 0.f, 0.f};

  for (int it = 0; it < NIT; ++it) {
    const int cur = it & 1;
    const int j0 = jbase + it * TJ;
    if (it + 1 < NIT) {
      *(float4*)((char*)&vbuf[jq][cur ^ 1][0] + tc * 16) = pB0;
      *(float4*)((char*)&vbuf[jq][cur ^ 1][0] + (tc + 128) * 16) = pB1;
    }
    if (it + 2 < NIT) {
      pB0 = *(const float4*)(hBp + (size_t)((j0 + 2 * TJ) >> 5) * 8192 + tc * 16);
      pB1 = *(const float4*)(hBp + (size_t)((j0 + 2 * TJ) >> 5) * 8192 + (tc + 128) * 16);
    }
    unsigned short nk = 0;
    if (it + 1 < NIT) nk = mp[(size_t)((j0 + TJ) >> 6) * 64];

    uint4 e1u = *(const uint4*)((const char*)&ets[0][j0] + quad * 16);
    uint4 e2u = *(const uint4*)((const char*)&ets[1][j0] + quad * 16);
    const unsigned int mbyte = ((unsigned int)mk >> (8 * ((j0 >> 5) & 1))) & 0xffu;
    const uint2 mA = mlut[mbyte & 15u];
    const uint2 mB = mlut[mbyte >> 4];
    union { unsigned int u[4]; f16x8 v8; } af;
    af.u[0] = wmax(Ep2, Eq2, e1u.x, e2u.x) & mA.x;
    af.u[1] = wmax(Ep2, Eq2, e1u.y, e2u.y) & mA.y;
    af.u[2] = wmax(Ep2, Eq2, e1u.z, e2u.z) & mB.x;
    af.u[3] = wmax(Ep2, Eq2, e1u.w, e2u.w) & mB.y;
    const f16x8 a = af.v8;
    acc5 = __builtin_amdgcn_mfma_f32_16x16x32_f16(a, ones, acc5, 0, 0, 0);
    const __fp16* vb = &vbuf[jq][cur][0];
    #pragma unroll
    for (int t = 0; t < 4; ++t) {
      f16x8 bf = *(const f16x8*)(vb + t * 512 + l * 8);
      acc[t] = __builtin_amdgcn_mfma_f32_16x16x32_f16(a, bf, acc[t], 0, 0, 0);
    }
    mk = nk;
    __syncthreads();
  }

  // combine across 4 j-chunks (overlay: pacc 24 KB in vbuf, pls after it)
  auto pacc = (float(*)[NRG][16][64])(&vbuf[0][0][0]);
  auto pls  = (float(*)[NRG][16])((char*)&vbuf[0][0][0] + 24576);
  if (jq > 0) {
    #pragma unroll
    for (int t = 0; t < 4; ++t)
      #pragma unroll
      for (int r = 0; r < 4; ++r)
        pacc[jq - 1][rowg][quad * 4 + r][t * 16 + c15] = acc[t][r];
    if (c15 == 0) {
      #pragma unroll
      for (int r = 0; r < 4; ++r) pls[jq - 1][rowg][quad * 4 + r] = acc5[r];
    }
  }
  __syncthreads();
  if (jq == 0) {
    float Lrow[4];
    #pragma unroll
    for (int r = 0; r < 4; ++r) Lrow[r] = acc5[r];
    #pragma unroll
    for (int q = 0; q < NJQ - 1; ++q) {
      #pragma unroll
      for (int t = 0; t < 4; ++t)
        #pragma unroll
        for (int r = 0; r < 4; ++r)
          acc[t][r] += pacc[q][rowg][quad * 4 + r][t * 16 + c15];
      #pragma unroll
      for (int r = 0; r < 4; ++r) Lrow[r] += pls[q][rowg][quad * 4 + r];
    }
    float lr[4];
    #pragma unroll
    for (int r = 0; r < 4; ++r) lr[r] = 1.f / Lrow[r];
    #pragma unroll
    for (int t = 0; t < 4; ++t) {
      const float bv = bias[fs * 64 + t * 16 + c15];
      #pragma unroll
      for (int r = 0; r < 4; ++r) {
        const int i = i0w + quad * 4 + r;
        float v = acc[t][r] * lr[r] + bv;
        out[(size_t)(b * N_ + i) * 128 + fs * 64 + t * 16 + c15] = fmaxf(v, 0.f);
      }
    }
  }
}

// ---------------------------------------------------------------------------
extern "C" void kernel_launch(void* const* d_in, const int* in_sizes, int n_in,
                              void* d_out, int out_size, void* d_ws, size_t ws_size,
                              hipStream_t stream) {
  const float* x   = (const float*)d_in[0];
  const int*   adj = (const int*)d_in[1];
  const float* Wh  = (const float*)d_in[2];
  const float* ah  = (const float*)d_in[3];
  const float* bh  = (const float*)d_in[4];
  const float* Wo  = (const float*)d_in[5];
  const float* ao  = (const float*)d_in[6];
  const float* bo  = (const float*)d_in[7];
  float* out = (float*)d_out;

  float* ws   = (float*)d_ws;
  float* s1h  = ws;                                   // B*8*N
  float* s2h  = s1h  + (size_t)B_ * NHEADS_ * N_;     // (unused; keeps layout)
  float* s1o  = s2h  + (size_t)B_ * NHEADS_ * N_;     // B*N
  float* s2o  = s1o  + (size_t)B_ * N_;               // (unused; keeps layout)
  __fp16* g1  = (__fp16*)(s2o + (size_t)B_ * N_);     // B*N*512 f16 (8 MB)
  __fp16* hB1 = g1  + (size_t)B_ * N_ * 512;          // 8 MB
  __fp16* hB2 = hB1 + (size_t)B_ * NHEADS_ * N_ * 64; // 2 MB
  __fp16* WhB = hB2 + (size_t)B_ * N_ * 128;          // 256 KB
  __fp16* WoB = WhB + (size_t)8 * 256 * 64;           // 128 KB
  unsigned short* mask2 = (unsigned short*)(WoB + (size_t)512 * 128); // 2 MB
  __fp16* e1h = (__fp16*)(mask2 + (size_t)B_ * 128 * 32 * 64);  // 128 KB
  __fp16* e2h = e1h + (size_t)B_ * NHEADS_ * N_;                // 128 KB
  __fp16* e1o = e2h + (size_t)B_ * NHEADS_ * N_;                // 16 KB
  __fp16* e2o = e1o + (size_t)B_ * N_;                          // 16 KB
  float* pmx1 = (float*)(e2o + (size_t)B_ * N_);                // 16 KB
  float* pmx2 = pmx1 + (size_t)B_ * NHEADS_ * 128;              // 2 KB

  k_prep<<<4192, 256, 0, stream>>>(adj, mask2, Wh, WhB, Wo, WoB);
  k_gemm1<<<B_ * (N_ / 16), 256, 0, stream>>>(x, WhB, ah, hB1, s1h, e1h, e2h, pmx1);
  k_att1<<<B_ * NHEADS_ * (N_ / 128), 512, 0, stream>>>(
      hB1, s1h, e1h, e2h, pmx1, mask2, bh, g1);
  k_gemm2<<<B_ * (N_ / 16), 256, 0, stream>>>(g1, WoB, ao, hB2, s1o, e1o, e2o, pmx2);
  k_att2<<<B_ * 2 * (N_ / 32), 512, 0, stream>>>(
      hB2, s1o, e1o, e2o, pmx2, mask2, bo, out);
}

// Round 11
// 174.842 us; speedup vs baseline: 1.2027x; 1.0450x over previous
//
#include <hip/hip_runtime.h>

constexpr int B_ = 4;
constexpr int N_ = 2048;
constexpr int NFEAT_ = 256;
constexpr int NHEADS_ = 8;
constexpr float SLOPE_ = 0.1f;
constexpr float L2E = 1.4426950408889634f;   // log2(e)

typedef __attribute__((ext_vector_type(8))) __fp16 f16x8;
typedef __attribute__((ext_vector_type(4))) __fp16 f16x4;
typedef __attribute__((ext_vector_type(2))) __fp16 f16x2;
typedef __attribute__((ext_vector_type(4))) float f32x4;

__device__ __forceinline__ f16x8 pack8(const float* v) {
  union { f16x2 h2[4]; f16x8 h8; } u;
  u.h2[0] = __builtin_amdgcn_cvt_pkrtz(v[0], v[1]);
  u.h2[1] = __builtin_amdgcn_cvt_pkrtz(v[2], v[3]);
  u.h2[2] = __builtin_amdgcn_cvt_pkrtz(v[4], v[5]);
  u.h2[3] = __builtin_amdgcn_cvt_pkrtz(v[6], v[7]);
  return u.h8;
}
__device__ __forceinline__ f16x4 pack4(float a, float b, float c, float d) {
  union { f16x2 h2[2]; f16x4 h4; } u;
  u.h2[0] = __builtin_amdgcn_cvt_pkrtz(a, b);
  u.h2[1] = __builtin_amdgcn_cvt_pkrtz(c, d);
  return u.h4;
}

// weight pair = max(Ep*E1pair, Eq*E2pair) in packed f16 (exp2 is monotone, so
// exp2(max(t0,t1)) == max(exp2 t0, exp2 t1); both branches factor row x col).
__device__ __forceinline__ unsigned int wmax(f16x2 Ep2, f16x2 Eq2,
                                             unsigned int e1p, unsigned int e2p) {
  f16x2 ea, eb;
  __builtin_memcpy(&ea, &e1p, 4);
  __builtin_memcpy(&eb, &e2p, 4);
  f16x2 a, b, c;
  asm("v_pk_mul_f16 %0, %1, %2" : "=v"(a) : "v"(Ep2), "v"(ea));
  asm("v_pk_mul_f16 %0, %1, %2" : "=v"(b) : "v"(Eq2), "v"(eb));
  asm("v_pk_max_f16 %0, %1, %2" : "=v"(c) : "v"(a), "v"(b));
  unsigned int r;
  __builtin_memcpy(&r, &c, 4);
  return r;
}

// ---------------------------------------------------------------------------
// Fused prep: blocks [0,4096) packmask; [4096,4160) prepWh; [4160,4192) prepWo
// ---------------------------------------------------------------------------
__global__ __launch_bounds__(256) void k_prep(
    const int* __restrict__ adj, unsigned short* __restrict__ mask2,
    const float* __restrict__ Wh, __fp16* __restrict__ WhB,
    const float* __restrict__ Wo, __fp16* __restrict__ WoB)
{
  const int bid = blockIdx.x;
  const int l = threadIdx.x & 63;
  if (bid < 4096) {
    const size_t gw = ((size_t)bid * 256 + threadIdx.x) >> 6;
    const int jt = (int)(gw & 31);
    const int ig16 = (int)((gw >> 5) & 127);
    const int b = (int)(gw >> 12);
    const int q = l >> 4, c15 = l & 15;
    const int* base = adj + ((size_t)b * N_ + ig16 * 16) * N_ + jt * 64 + l;
    unsigned int msk = 0;
    #pragma unroll
    for (int r = 0; r < 16; ++r) {
      int a = base[(size_t)r * N_];
      unsigned long long bal = __ballot(a > 0);
      unsigned int v = (unsigned int)((bal >> (q * 8)) & 0xffull)
                     | ((unsigned int)((bal >> (q * 8 + 32)) & 0xffull) << 8);
      if (r == c15) msk = v;
    }
    mask2[gw * 64 + l] = (unsigned short)msk;
  } else if (bid < 4160) {
    int s = (int)(((bid - 4096) * 256 + threadIdx.x) >> 6);   // 0..255
    int h = s >> 5, ks = (s >> 2) & 7, ft = s & 3;
    const float* src = Wh + ((size_t)h * 256 + ks * 32 + (l >> 4) * 8) * 64 + ft * 16 + (l & 15);
    float v[8];
    #pragma unroll
    for (int j = 0; j < 8; ++j) v[j] = src[(size_t)j * 64];
    *(f16x8*)(WhB + (size_t)s * 512 + l * 8) = pack8(v);
  } else {
    int s = (int)(((bid - 4160) * 256 + threadIdx.x) >> 6);   // 0..127
    int ks = s >> 3, ft = s & 7;
    const float* src = Wo + ((size_t)ks * 32 + (l >> 4) * 8) * 128 + ft * 16 + (l & 15);
    float v[8];
    #pragma unroll
    for (int j = 0; j < 8; ++j) v[j] = src[(size_t)j * 128];
    *(f16x8*)(WoB + (size_t)s * 512 + l * 8) = pack8(v);
  }
}

// ---------------------------------------------------------------------------
// GEMM1 (MFMA): block = 16 n-rows x ALL 512 f (8 heads), 256 thr = 4 waves.
// Epilogue emits exp2 column tables e1h/e2h + per-(block,head) partial max
// (plain store, NO atomics).
// ---------------------------------------------------------------------------
__global__ __launch_bounds__(256, 4) void k_gemm1(
    const float* __restrict__ x, const __fp16* __restrict__ WhB,
    const float* __restrict__ ah,
    __fp16* __restrict__ hB1, float* __restrict__ s1h,
    __fp16* __restrict__ e1h, __fp16* __restrict__ e2h,
    float* __restrict__ pmx1)
{
  constexpr int XP = 264;
  __shared__ __fp16 xs[16 * XP];
  __shared__ __fp16 hT[512 * 16];

  const int t = threadIdx.x;
  const int bid = blockIdx.x;
  const int b = bid >> 7;
  const int n0 = (bid & 127) * 16;

  {  // stage x -> f16
    int r = t >> 4, k0 = (t & 15) * 16;
    const float* src = x + ((size_t)(b * N_) + n0 + r) * NFEAT_ + k0;
    float v0[8], v1[8];
    *(float4*)&v0[0] = *(const float4*)(src);
    *(float4*)&v0[4] = *(const float4*)(src + 4);
    *(float4*)&v1[0] = *(const float4*)(src + 8);
    *(float4*)&v1[4] = *(const float4*)(src + 12);
    *(f16x8*)&xs[r * XP + k0] = pack8(v0);
    *(f16x8*)&xs[r * XP + k0 + 8] = pack8(v1);
  }
  __syncthreads();

  const int w = t >> 6, l = t & 63;
  const int quad = l >> 4, c15 = l & 15;

  f32x4 acc[8];
  #pragma unroll
  for (int i = 0; i < 8; ++i) acc[i] = (f32x4){0.f, 0.f, 0.f, 0.f};

  for (int ks = 0; ks < 8; ++ks) {
    f16x8 af = *(const f16x8*)&xs[c15 * XP + ks * 32 + quad * 8];
    #pragma unroll
    for (int tt = 0; tt < 8; ++tt) {
      int hl = tt >> 2, ft = tt & 3;
      f16x8 bf = *(const f16x8*)(WhB +
          ((((size_t)(2 * w + hl) * 8 + ks) * 4 + ft) * 512) + l * 8);
      acc[tt] = __builtin_amdgcn_mfma_f32_16x16x32_f16(af, bf, acc[tt], 0, 0, 0);
    }
  }

  #pragma unroll
  for (int hl = 0; hl < 2; ++hl) {
    int head = 2 * w + hl;
    float a1v[4], a2v[4];
    #pragma unroll
    for (int ft = 0; ft < 4; ++ft) {
      a1v[ft] = ah[head * 128 + ft * 16 + c15] * L2E;
      a2v[ft] = ah[head * 128 + 64 + ft * 16 + c15] * L2E;
    }
    float hmax = -1e30f;
    #pragma unroll
    for (int r = 0; r < 4; ++r) {
      float v1 = 0.f, v2 = 0.f;
      #pragma unroll
      for (int ft = 0; ft < 4; ++ft) {
        v1 = fmaf(acc[hl * 4 + ft][r], a1v[ft], v1);
        v2 = fmaf(acc[hl * 4 + ft][r], a2v[ft], v2);
      }
      #pragma unroll
      for (int off = 1; off < 16; off <<= 1) {
        v1 += __shfl_xor(v1, off, 64);
        v2 += __shfl_xor(v2, off, 64);
      }
      if (c15 == 0) {
        const size_t nn = (size_t)(b * NHEADS_ + head) * N_ + n0 + quad * 4 + r;
        s1h[nn] = v1;
        e1h[nn] = (__fp16)__builtin_amdgcn_exp2f(v2);
        e2h[nn] = (__fp16)__builtin_amdgcn_exp2f(SLOPE_ * v2);
      }
      hmax = fmaxf(hmax, v2);
    }
    hmax = fmaxf(hmax, __shfl_xor(hmax, 16, 64));
    hmax = fmaxf(hmax, __shfl_xor(hmax, 32, 64));
    if (l == 0)
      pmx1[(size_t)(b * NHEADS_ + head) * 128 + (n0 >> 4)] = hmax;
  }

  #pragma unroll
  for (int tt = 0; tt < 8; ++tt) {
    int f = (2 * w + (tt >> 2)) * 64 + (tt & 3) * 16 + c15;
    *(f16x4*)&hT[f * 16 + quad * 4] =
        pack4(acc[tt][0], acc[tt][1], acc[tt][2], acc[tt][3]);
  }
  __syncthreads();

  const int base_oct = (n0 >> 3) & 3;
  #pragma unroll
  for (int q = 0; q < 4; ++q) {
    int s = t + q * 256;
    int c15v = s & 15, oct = (s >> 4) & 1, ft = (s >> 5) & 3, head = s >> 7;
    f16x8 v = *(const f16x8*)&hT[(head * 64 + ft * 16 + c15v) * 16 + oct * 8];
    int lane0 = (base_oct + oct) * 16 + c15v;
    *(f16x8*)(hB1 +
        ((((size_t)(b * NHEADS_ + head) * 64 + (n0 >> 5)) * 4 + ft) * 512) + lane0 * 8) = v;
  }
}

// ---------------------------------------------------------------------------
// GEMM2 (MFMA): block = 16 n-rows x 128 f, 256 thr = 4 waves.
// Epilogue emits e1o/e2o tables + per-block partial max (plain store).
// ---------------------------------------------------------------------------
__global__ __launch_bounds__(256, 4) void k_gemm2(
    const __fp16* __restrict__ g1, const __fp16* __restrict__ WoB,
    const float* __restrict__ ao,
    __fp16* __restrict__ hB2, float* __restrict__ s1o,
    __fp16* __restrict__ e1o, __fp16* __restrict__ e2o,
    float* __restrict__ pmx2)
{
  constexpr int GP = 520;
  __shared__ __fp16 gs[16 * GP];
  __shared__ __fp16 hT[128 * 16];
  __shared__ float sd1[4][16], sd2[4][16];

  const int t = threadIdx.x;
  const int bid = blockIdx.x;
  const int b = bid >> 7;
  const int n0 = (bid & 127) * 16;

  {
    int r = t >> 4, k0 = (t & 15) * 32;
    const __fp16* src = g1 + ((size_t)(b * N_) + n0 + r) * 512 + k0;
    #pragma unroll
    for (int i = 0; i < 4; ++i)
      *(f16x8*)&gs[r * GP + k0 + i * 8] = *(const f16x8*)(src + i * 8);
  }
  __syncthreads();

  const int w = t >> 6, l = t & 63;
  const int quad = l >> 4, c15 = l & 15;

  f32x4 acc[2];
  acc[0] = (f32x4){0.f, 0.f, 0.f, 0.f};
  acc[1] = (f32x4){0.f, 0.f, 0.f, 0.f};

  for (int ks = 0; ks < 16; ++ks) {
    f16x8 af = *(const f16x8*)&gs[c15 * GP + ks * 32 + quad * 8];
    #pragma unroll
    for (int tt = 0; tt < 2; ++tt) {
      int ft = 2 * w + tt;
      f16x8 bf = *(const f16x8*)(WoB + (((size_t)ks * 8 + ft) * 512) + l * 8);
      acc[tt] = __builtin_amdgcn_mfma_f32_16x16x32_f16(af, bf, acc[tt], 0, 0, 0);
    }
  }

  {
    float a1v[2], a2v[2];
    #pragma unroll
    for (int tt = 0; tt < 2; ++tt) {
      int f = (2 * w + tt) * 16 + c15;
      a1v[tt] = ao[f] * L2E;
      a2v[tt] = ao[128 + f] * L2E;
    }
    #pragma unroll
    for (int r = 0; r < 4; ++r) {
      float v1 = acc[0][r] * a1v[0] + acc[1][r] * a1v[1];
      float v2 = acc[0][r] * a2v[0] + acc[1][r] * a2v[1];
      #pragma unroll
      for (int off = 1; off < 16; off <<= 1) {
        v1 += __shfl_xor(v1, off, 64);
        v2 += __shfl_xor(v2, off, 64);
      }
      if (c15 == 0) { sd1[w][quad * 4 + r] = v1; sd2[w][quad * 4 + r] = v2; }
    }
  }

  #pragma unroll
  for (int tt = 0; tt < 2; ++tt) {
    int f = (2 * w + tt) * 16 + c15;
    *(f16x4*)&hT[f * 16 + quad * 4] =
        pack4(acc[tt][0], acc[tt][1], acc[tt][2], acc[tt][3]);
  }
  __syncthreads();

  if (t < 16)
    s1o[(size_t)b * N_ + n0 + t] = sd1[0][t] + sd1[1][t] + sd1[2][t] + sd1[3][t];
  else if (t < 32) {
    int rr = t - 16;
    float v = sd2[0][rr] + sd2[1][rr] + sd2[2][rr] + sd2[3][rr];
    e1o[(size_t)b * N_ + n0 + rr] = (__fp16)__builtin_amdgcn_exp2f(v);
    e2o[(size_t)b * N_ + n0 + rr] = (__fp16)__builtin_amdgcn_exp2f(SLOPE_ * v);
    float hm = v;
    hm = fmaxf(hm, __shfl_xor(hm, 1, 64));
    hm = fmaxf(hm, __shfl_xor(hm, 2, 64));
    hm = fmaxf(hm, __shfl_xor(hm, 4, 64));
    hm = fmaxf(hm, __shfl_xor(hm, 8, 64));
    if (rr == 0) pmx2[(size_t)b * 128 + (n0 >> 4)] = hm;
  }

  {
    int c15v = t & 15, oct = (t >> 4) & 1, ft = t >> 5;
    f16x8 v = *(const f16x8*)&hT[(ft * 16 + c15v) * 16 + oct * 8];
    int base_oct = (n0 >> 3) & 3;
    int lane0 = (base_oct + oct) * 16 + c15v;
    *(f16x8*)(hB2 +
        (((size_t)(b * 64 + (n0 >> 5)) * 8 + ft) * 512) + lane0 * 8) = v;
  }
}

// ---------------------------------------------------------------------------
// ATT1 (R8 best config, exact revert): block = 128 rows, 8 waves x 16 rows,
// every wave sweeps the FULL 2048 j against ONE shared double-buffered V tile
// (TJ=128); E tables staged in LDS; depth-2 reg staging; factorized weights;
// pmx row max; no combine epilogue. Measured ~33.5 us / total 177.2 us.
// R9 (2-tile/wave) and R10 (direct-global E) both regressed — this is the
// verified local optimum.
// ---------------------------------------------------------------------------
__global__ __launch_bounds__(512, 4) void k_att1(
    const __fp16* __restrict__ hB, const float* __restrict__ s1,
    const __fp16* __restrict__ e1, const __fp16* __restrict__ e2,
    const float* __restrict__ pmx1,
    const unsigned short* __restrict__ mask2,
    const float* __restrict__ bias, __fp16* __restrict__ g1)
{
  constexpr int TJ = 128, NIT = N_ / TJ;       // 16 iterations
  constexpr int TILE = TJ * 64;                // 8192 f16 = 16 KB / slot

  __shared__ __fp16 vbuf[2][TILE];             // 32 KB (shared by all 8 waves)
  __shared__ __fp16 ets[2][N_];                // 8 KB (E1, E2 tables)
  __shared__ uint2 mlut[16];                   // nibble -> 2 packed pair masks

  const int tid = threadIdx.x;
  const int w = tid >> 6, l = tid & 63;
  const int quad = l >> 4, c15 = l & 15;

  int idx = blockIdx.x;
  const int ig = idx & 15; idx >>= 4;          // N/128 = 16 row-tiles
  const int head = idx & 7;
  const int b = idx >> 3;
  const int i0w = ig * 128 + w * 16;           // wave's 16-row group
  const int bh = b * NHEADS_ + head;

  const float* s1p = s1 + (size_t)bh * N_;
  const char* hBp = (const char*)(hB + (size_t)bh * (N_ / 32) * 2048);
  const unsigned short* mp = mask2 + ((size_t)(b * 128 + (i0w >> 4)) * 32) * 64 + l;

  if (tid < 16) {
    unsigned int v = tid;
    mlut[tid] = (uint2){ ((v & 1u) ? 0xffffu : 0u) | ((v & 2u) ? 0xffff0000u : 0u),
                         ((v & 4u) ? 0xffffu : 0u) | ((v & 8u) ? 0xffff0000u : 0u) };
  }

  // depth-2 prologue: tiles 0 and 1 in flight (16 KB each, 2 float4/thread)
  float4 pA0 = *(const float4*)(hBp + tid * 16);
  float4 pA1 = *(const float4*)(hBp + 8192 + tid * 16);
  float4 pB0 = *(const float4*)(hBp + 16384 + tid * 16);
  float4 pB1 = *(const float4*)(hBp + 16384 + 8192 + tid * 16);
  unsigned short mk0 = mp[0];
  unsigned short mk1 = mp[64];

  {  // stage E tables: 512 threads x 16 B covers both 4 KB tables
    const int half = tid >> 8, off = (tid & 255) * 8;
    const __fp16* src = (half ? e2 : e1) + (size_t)bh * N_ + off;
    *(f16x8*)&ets[half][off] = *(const f16x8*)src;
  }

  const float s1v = s1p[i0w + c15];
  // row max of s2 from the 128 partials (every wave redundantly)
  float s2m;
  {
    const float* pm = pmx1 + (size_t)bh * 128;
    float tmx = fmaxf(pm[l], pm[l + 64]);
    #pragma unroll
    for (int off = 1; off < 64; off <<= 1)
      tmx = fmaxf(tmx, __shfl_xor(tmx, off, 64));
    s2m = tmx;
  }
  // write tile 0 (vmcnt on pA elapsed under the staging above)
  *(float4*)((char*)&vbuf[0][0] + tid * 16) = pA0;
  *(float4*)((char*)&vbuf[0][0] + 8192 + tid * 16) = pA1;
  __syncthreads();

  const float zm = s1v + s2m;
  const float m = fmaxf(zm, SLOPE_ * zm);      // exact unmasked row max
  const float Ep = __builtin_amdgcn_exp2f(s1v - m);
  const float Eq = __builtin_amdgcn_exp2f(SLOPE_ * s1v - m);
  const f16x2 Ep2 = __builtin_amdgcn_cvt_pkrtz(Ep, Ep);
  const f16x2 Eq2 = __builtin_amdgcn_cvt_pkrtz(Eq, Eq);

  f16x8 ones;
  #pragma unroll
  for (int i = 0; i < 8; ++i) ones[i] = (__fp16)1.0f;

  f32x4 acc[4], acc5;
  #pragma unroll
  for (int t = 0; t < 4; ++t) acc[t] = (f32x4){0.f, 0.f, 0.f, 0.f};
  acc5 = (f32x4){0.f, 0.f, 0.f, 0.f};

  for (int it = 0; it < NIT; ++it) {
    const int cur = it & 1;
    if (it + 1 < NIT) {    // write tile it+1 (regs loaded >=1 iter ago: free)
      *(float4*)((char*)&vbuf[cur ^ 1][0] + tid * 16) = pB0;
      *(float4*)((char*)&vbuf[cur ^ 1][0] + 8192 + tid * 16) = pB1;
    }
    if (it + 2 < NIT) {    // issue loads for tile it+2 (full-iter cover)
      const char* srcb = hBp + (size_t)(it + 2) * 16384;
      pB0 = *(const float4*)(srcb + tid * 16);
      pB1 = *(const float4*)(srcb + 8192 + tid * 16);
    }
    unsigned short nk0 = 0, nk1 = 0;
    if (it + 1 < NIT) {
      nk0 = mp[(size_t)(it + 1) * 128];
      nk1 = mp[(size_t)(it + 1) * 128 + 64];
    }

    #pragma unroll
    for (int h = 0; h < 4; ++h) {              // 4 ksteps of 32 j
      const int jk = it * TJ + h * 32;
      uint4 e1u = *(const uint4*)((const char*)&ets[0][jk] + quad * 16);
      uint4 e2u = *(const uint4*)((const char*)&ets[1][jk] + quad * 16);
      const unsigned int mword = (h < 2) ? (unsigned int)mk0 : (unsigned int)mk1;
      const unsigned int mbyte = (mword >> (8 * (h & 1))) & 0xffu;
      const uint2 mA = mlut[mbyte & 15u];
      const uint2 mB = mlut[mbyte >> 4];
      union { unsigned int u[4]; f16x8 v8; } af;
      af.u[0] = wmax(Ep2, Eq2, e1u.x, e2u.x) & mA.x;
      af.u[1] = wmax(Ep2, Eq2, e1u.y, e2u.y) & mA.y;
      af.u[2] = wmax(Ep2, Eq2, e1u.z, e2u.z) & mB.x;
      af.u[3] = wmax(Ep2, Eq2, e1u.w, e2u.w) & mB.y;
      const f16x8 a = af.v8;
      acc5 = __builtin_amdgcn_mfma_f32_16x16x32_f16(a, ones, acc5, 0, 0, 0);
      const __fp16* vb = &vbuf[cur][h * 2048];
      #pragma unroll
      for (int t = 0; t < 4; ++t) {
        f16x8 bf = *(const f16x8*)(vb + t * 512 + l * 8);
        acc[t] = __builtin_amdgcn_mfma_f32_16x16x32_f16(a, bf, acc[t], 0, 0, 0);
      }
    }
    mk0 = nk0; mk1 = nk1;
    __syncthreads();
  }

  // epilogue: per-wave direct write (acc5 is the full-row denominator)
  float lr[4];
  #pragma unroll
  for (int r = 0; r < 4; ++r) lr[r] = 1.f / acc5[r];
  #pragma unroll
  for (int t = 0; t < 4; ++t) {
    const float bv = bias[head * 64 + t * 16 + c15];
    #pragma unroll
    for (int r = 0; r < 4; ++r) {
      const int i = i0w + quad * 4 + r;
      float v = acc[t][r] * lr[r] + bv;
      v = (v > 0.f) ? v : expm1f(v);            // elu
      g1[(size_t)(b * N_ + i) * 512 + head * 64 + t * 16 + c15] = (__fp16)v;
    }
  }
}

// ---------------------------------------------------------------------------
// ATT2 (R8 config): factorized weights + depth-2 staging. 512 blocks of
// 32 rows x 64 cols; 8 waves = 2 rowg x 4 jq of 512; TJ=32.
// ---------------------------------------------------------------------------
__global__ __launch_bounds__(512, 4) void k_att2(
    const __fp16* __restrict__ hB, const float* __restrict__ s1,
    const __fp16* __restrict__ e1, const __fp16* __restrict__ e2,
    const float* __restrict__ pmx2,
    const unsigned short* __restrict__ mask2,
    const float* __restrict__ bias, float* __restrict__ out)
{
  constexpr int NRG = 2, NJQ = 4, JLEN = 512, TJ = 32, NIT = JLEN / TJ;
  constexpr int TILE = TJ * 64;                // 2048 f16 / slot (4 KB)

  __shared__ __fp16 vbuf[NJQ][2][TILE];        // 32 KB
  __shared__ __fp16 ets[2][N_];                // 8 KB
  __shared__ uint2 mlut[16];

  const int tid = threadIdx.x;
  const int w = tid >> 6, l = tid & 63;
  const int quad = l >> 4, c15 = l & 15;
  const int rowg = w % NRG, jq = w / NRG;
  const int tc = rowg * 64 + l;                // [0,128)

  int idx = blockIdx.x;
  const int ig = idx & 63; idx >>= 6;
  const int fs = idx & 1;
  const int b = idx >> 1;
  const int i0w = ig * 32 + rowg * 16;

  const float* s1p = s1 + (size_t)b * N_;
  const char* hBp = (const char*)(hB + (size_t)b * 64 * 4096 + fs * 2048);
  const unsigned short* mp = mask2 + ((size_t)(b * 128 + (i0w >> 4)) * 32) * 64 + l;

  const int jbase = jq * JLEN;

  if (tid < 16) {
    unsigned int v = tid;
    mlut[tid] = (uint2){ ((v & 1u) ? 0xffffu : 0u) | ((v & 2u) ? 0xffff0000u : 0u),
                         ((v & 4u) ? 0xffffu : 0u) | ((v & 8u) ? 0xffff0000u : 0u) };
  }

  float4 pA0 = *(const float4*)(hBp + (size_t)(jbase >> 5) * 8192 + tc * 16);
  float4 pA1 = *(const float4*)(hBp + (size_t)(jbase >> 5) * 8192 + (tc + 128) * 16);
  float4 pB0 = *(const float4*)(hBp + (size_t)((jbase + TJ) >> 5) * 8192 + tc * 16);
  float4 pB1 = *(const float4*)(hBp + (size_t)((jbase + TJ) >> 5) * 8192 + (tc + 128) * 16);
  unsigned short mk = mp[(size_t)(jbase >> 6) * 64];

  {
    const int half = tid >> 8, off = (tid & 255) * 8;
    const __fp16* src = (half ? e2 : e1) + (size_t)b * N_ + off;
    *(f16x8*)&ets[half][off] = *(const f16x8*)src;
  }

  const float s1v = s1p[i0w + c15];
  float s2m;
  {
    const float* pm = pmx2 + (size_t)b * 128;
    float tmx = fmaxf(pm[l], pm[l + 64]);
    #pragma unroll
    for (int off = 1; off < 64; off <<= 1)
      tmx = fmaxf(tmx, __shfl_xor(tmx, off, 64));
    s2m = tmx;
  }
  *(float4*)((char*)&vbuf[jq][0][0] + tc * 16) = pA0;
  *(float4*)((char*)&vbuf[jq][0][0] + (tc + 128) * 16) = pA1;
  __syncthreads();

  const float zm = s1v + s2m;
  const float m = fmaxf(zm, SLOPE_ * zm);
  const float Ep = __builtin_amdgcn_exp2f(s1v - m);
  const float Eq = __builtin_amdgcn_exp2f(SLOPE_ * s1v - m);
  const f16x2 Ep2 = __builtin_amdgcn_cvt_pkrtz(Ep, Ep);
  const f16x2 Eq2 = __builtin_amdgcn_cvt_pkrtz(Eq, Eq);

  f16x8 ones;
  #pragma unroll
  for (int i = 0; i < 8; ++i) ones[i] = (__fp16)1.0f;

  f32x4 acc[4], acc5;
  #pragma unroll
  for (int t = 0; t < 4; ++t) acc[t] = (f32x4){0.f, 0.f, 0.f, 0.f};
  acc5 = (f32x4){0.f, 0.f, 0.f, 0.f};

  for (int it = 0; it < NIT; ++it) {
    const int cur = it & 1;
    const int j0 = jbase + it * TJ;
    if (it + 1 < NIT) {
      *(float4*)((char*)&vbuf[jq][cur ^ 1][0] + tc * 16) = pB0;
      *(float4*)((char*)&vbuf[jq][cur ^ 1][0] + (tc + 128) * 16) = pB1;
    }
    if (it + 2 < NIT) {
      pB0 = *(const float4*)(hBp + (size_t)((j0 + 2 * TJ) >> 5) * 8192 + tc * 16);
      pB1 = *(const float4*)(hBp + (size_t)((j0 + 2 * TJ) >> 5) * 8192 + (tc + 128) * 16);
    }
    unsigned short nk = 0;
    if (it + 1 < NIT) nk = mp[(size_t)((j0 + TJ) >> 6) * 64];

    uint4 e1u = *(const uint4*)((const char*)&ets[0][j0] + quad * 16);
    uint4 e2u = *(const uint4*)((const char*)&ets[1][j0] + quad * 16);
    const unsigned int mbyte = ((unsigned int)mk >> (8 * ((j0 >> 5) & 1))) & 0xffu;
    const uint2 mA = mlut[mbyte & 15u];
    const uint2 mB = mlut[mbyte >> 4];
    union { unsigned int u[4]; f16x8 v8; } af;
    af.u[0] = wmax(Ep2, Eq2, e1u.x, e2u.x) & mA.x;
    af.u[1] = wmax(Ep2, Eq2, e1u.y, e2u.y) & mA.y;
    af.u[2] = wmax(Ep2, Eq2, e1u.z, e2u.z) & mB.x;
    af.u[3] = wmax(Ep2, Eq2, e1u.w, e2u.w) & mB.y;
    const f16x8 a = af.v8;
    acc5 = __builtin_amdgcn_mfma_f32_16x16x32_f16(a, ones, acc5, 0, 0, 0);
    const __fp16* vb = &vbuf[jq][cur][0];
    #pragma unroll
    for (int t = 0; t < 4; ++t) {
      f16x8 bf = *(const f16x8*)(vb + t * 512 + l * 8);
      acc[t] = __builtin_amdgcn_mfma_f32_16x16x32_f16(a, bf, acc[t], 0, 0, 0);
    }
    mk = nk;
    __syncthreads();
  }

  // combine across 4 j-chunks (overlay: pacc 24 KB in vbuf, pls after it)
  auto pacc = (float(*)[NRG][16][64])(&vbuf[0][0][0]);
  auto pls  = (float(*)[NRG][16])((char*)&vbuf[0][0][0] + 24576);
  if (jq > 0) {
    #pragma unroll
    for (int t = 0; t < 4; ++t)
      #pragma unroll
      for (int r = 0; r < 4; ++r)
        pacc[jq - 1][rowg][quad * 4 + r][t * 16 + c15] = acc[t][r];
    if (c15 == 0) {
      #pragma unroll
      for (int r = 0; r < 4; ++r) pls[jq - 1][rowg][quad * 4 + r] = acc5[r];
    }
  }
  __syncthreads();
  if (jq == 0) {
    float Lrow[4];
    #pragma unroll
    for (int r = 0; r < 4; ++r) Lrow[r] = acc5[r];
    #pragma unroll
    for (int q = 0; q < NJQ - 1; ++q) {
      #pragma unroll
      for (int t = 0; t < 4; ++t)
        #pragma unroll
        for (int r = 0; r < 4; ++r)
          acc[t][r] += pacc[q][rowg][quad * 4 + r][t * 16 + c15];
      #pragma unroll
      for (int r = 0; r < 4; ++r) Lrow[r] += pls[q][rowg][quad * 4 + r];
    }
    float lr[4];
    #pragma unroll
    for (int r = 0; r < 4; ++r) lr[r] = 1.f / Lrow[r];
    #pragma unroll
    for (int t = 0; t < 4; ++t) {
      const float bv = bias[fs * 64 + t * 16 + c15];
      #pragma unroll
      for (int r = 0; r < 4; ++r) {
        const int i = i0w + quad * 4 + r;
        float v = acc[t][r] * lr[r] + bv;
        out[(size_t)(b * N_ + i) * 128 + fs * 64 + t * 16 + c15] = fmaxf(v, 0.f);
      }
    }
  }
}

// ---------------------------------------------------------------------------
extern "C" void kernel_launch(void* const* d_in, const int* in_sizes, int n_in,
                              void* d_out, int out_size, void* d_ws, size_t ws_size,
                              hipStream_t stream) {
  const float* x   = (const float*)d_in[0];
  const int*   adj = (const int*)d_in[1];
  const float* Wh  = (const float*)d_in[2];
  const float* ah  = (const float*)d_in[3];
  const float* bh  = (const float*)d_in[4];
  const float* Wo  = (const float*)d_in[5];
  const float* ao  = (const float*)d_in[6];
  const float* bo  = (const float*)d_in[7];
  float* out = (float*)d_out;

  float* ws   = (float*)d_ws;
  float* s1h  = ws;                                   // B*8*N
  float* s2h  = s1h  + (size_t)B_ * NHEADS_ * N_;     // (unused; keeps layout)
  float* s1o  = s2h  + (size_t)B_ * NHEADS_ * N_;     // B*N
  float* s2o  = s1o  + (size_t)B_ * N_;               // (unused; keeps layout)
  __fp16* g1  = (__fp16*)(s2o + (size_t)B_ * N_);     // B*N*512 f16 (8 MB)
  __fp16* hB1 = g1  + (size_t)B_ * N_ * 512;          // 8 MB
  __fp16* hB2 = hB1 + (size_t)B_ * NHEADS_ * N_ * 64; // 2 MB
  __fp16* WhB = hB2 + (size_t)B_ * N_ * 128;          // 256 KB
  __fp16* WoB = WhB + (size_t)8 * 256 * 64;           // 128 KB
  unsigned short* mask2 = (unsigned short*)(WoB + (size_t)512 * 128); // 2 MB
  __fp16* e1h = (__fp16*)(mask2 + (size_t)B_ * 128 * 32 * 64);  // 128 KB
  __fp16* e2h = e1h + (size_t)B_ * NHEADS_ * N_;                // 128 KB
  __fp16* e1o = e2h + (size_t)B_ * NHEADS_ * N_;                // 16 KB
  __fp16* e2o = e1o + (size_t)B_ * N_;                          // 16 KB
  float* pmx1 = (float*)(e2o + (size_t)B_ * N_);                // 16 KB
  float* pmx2 = pmx1 + (size_t)B_ * NHEADS_ * 128;              // 2 KB

  k_prep<<<4192, 256, 0, stream>>>(adj, mask2, Wh, WhB, Wo, WoB);
  k_gemm1<<<B_ * (N_ / 16), 256, 0, stream>>>(x, WhB, ah, hB1, s1h, e1h, e2h, pmx1);
  k_att1<<<B_ * NHEADS_ * (N_ / 128), 512, 0, stream>>>(
      hB1, s1h, e1h, e2h, pmx1, mask2, bh, g1);
  k_gemm2<<<B_ * (N_ / 16), 256, 0, stream>>>(g1, WoB, ao, hB2, s1o, e1o, e2o, pmx2);
  k_att2<<<B_ * 2 * (N_ / 32), 512, 0, stream>>>(
      hB2, s1o, e1o, e2o, pmx2, mask2, bo, out);
}